// Round 5
// baseline (513.290 us; speedup 1.0000x reference)
//
#include <hip/hip_runtime.h>
#include <hip/hip_bf16.h>
#include <cstddef>
#include <cstdint>

// Problem constants
#define D_MODEL 256
#define NHEAD   8
#define HDIM    32
#define NLEV    3
#define NPNT    4
#define DFF     1024
#define BATCH   8
#define LQ      3600
#define LIN     4725   // 60*60 + 30*30 + 15*15
#define MROWS   (BATCH*LQ)   // 28800; row order is (lq,b): m = lq*8 + b

typedef short bf16x8 __attribute__((ext_vector_type(8)));
typedef float f32x4  __attribute__((ext_vector_type(4)));

__device__ __forceinline__ unsigned short f2b(float x) {
    unsigned int u = __float_as_uint(x);
    unsigned int r = (u + 0x7fffu + ((u >> 16) & 1u)) >> 16;   // RNE
    return (unsigned short)r;
}
__device__ __forceinline__ float b2f(unsigned short s) {
    return __uint_as_float(((unsigned int)s) << 16);
}

// s_waitcnt imm: [3:0] vmcnt lo, [6:4] expcnt, [11:8] lgkmcnt, [15:14] vmcnt hi
// 0xC07F = lgkmcnt(0), vmcnt/expcnt no-wait  (drain LDS writes only)
#define WAIT_LGKM0() __builtin_amdgcn_s_waitcnt(0xC07F)
#define BARRIER()    __builtin_amdgcn_s_barrier()

// ---------------------------------------------------------------------------
// Merged prep: [0,7200) conv tgt->bf16; [7200,16650) conv src->bf16;
// [16650,17618) weight convert; [17618,17623) query_pos projections.
#define WTOT 991232
__global__ __launch_bounds__(256) void prep_kernel(
    const float* __restrict__ tgt, unsigned short* __restrict__ tgtb,
    const float* __restrict__ srcf, unsigned short* __restrict__ srcb,
    const float* __restrict__ w_in, const float* __restrict__ w_out,
    const float* __restrict__ w_val, const float* __restrict__ w_cross,
    const float* __restrict__ w_so, const float* __restrict__ w_aw,
    const float* __restrict__ w_f1, const float* __restrict__ w_f2,
    unsigned short* __restrict__ wdst,
    const float* __restrict__ qp, const float* __restrict__ so_b,
    const float* __restrict__ aw_b, float* __restrict__ qpv)
{
    const int bid = blockIdx.x;
    const int tid = threadIdx.x;
    if (bid < 7200) {
        int i = bid * 256 + tid;
        float4 v = ((const float4*)tgt)[i];
        ushort4 o; o.x = f2b(v.x); o.y = f2b(v.y); o.z = f2b(v.z); o.w = f2b(v.w);
        ((ushort4*)tgtb)[i] = o;
    } else if (bid < 16650) {
        int i = (bid - 7200) * 256 + tid;
        float4 v = ((const float4*)srcf)[i];
        ushort4 o; o.x = f2b(v.x); o.y = f2b(v.y); o.z = f2b(v.z); o.w = f2b(v.w);
        ((ushort4*)srcb)[i] = o;
    } else if (bid < 17618) {
        int idx = ((bid - 16650) * 256 + tid) * 4;
        if (idx >= WTOT) return;
        const float* src; int off;
        if      (idx < 196608) { src = w_in;    off = idx; }
        else if (idx < 262144) { src = w_out;   off = idx - 196608; }
        else if (idx < 327680) { src = w_val;   off = idx - 262144; }
        else if (idx < 393216) { src = w_cross; off = idx - 327680; }
        else if (idx < 442368) { src = w_so;    off = idx - 393216; }
        else if (idx < 466944) { src = w_aw;    off = idx - 442368; }
        else if (idx < 729088) { src = w_f1;    off = idx - 466944; }
        else                   { src = w_f2;    off = idx - 729088; }
        float4 v = *(const float4*)(src + off);
        ushort4 o; o.x = f2b(v.x); o.y = f2b(v.y); o.z = f2b(v.z); o.w = f2b(v.w);
        *(ushort4*)(wdst + idx) = o;
    } else {
        int o = (bid - 17618) * 256 + tid;
        if (o >= 768 + 192 + 96) return;
        const float* wrow;
        if (o < 768)       wrow = w_in + (size_t)o * D_MODEL;
        else if (o < 960)  wrow = w_so + (size_t)(o - 768) * D_MODEL;
        else               wrow = w_aw + (size_t)(o - 960) * D_MODEL;
        float acc = 0.f;
        for (int d = 0; d < D_MODEL; ++d) acc += qp[d] * wrow[d];
        qpv[o] = acc;
        if (o >= 768) {
            float bias = (o < 960) ? so_b[o - 768] : aw_b[o - 960];
            qpv[1056 + (o - 768)] = acc + bias;
        }
    }
}

// ---------------------------------------------------------------------------
// bf16 MFMA GEMM, 128x128 tile, BK=32, 2-deep software pipeline:
// global->VGPR loads for iter i+1 stay in flight across raw s_barrier while
// iter i computes (partial vmcnt drains inserted automatically at reg use).
// K % 64 == 0 required (all uses: 256).
__global__ __launch_bounds__(256) void gemm_bf16(
    const unsigned short* __restrict__ A,
    const unsigned short* __restrict__ W,
    const float* __restrict__ bias,
    const float* __restrict__ bias2, int b2lim,
    float* __restrict__ Cf, unsigned short* __restrict__ Cb,
    int M, int N, int K, int relu)
{
    __shared__ __align__(16) unsigned short As[2][4096];   // 128x32 per buf
    __shared__ __align__(16) unsigned short Bs[2][4096];
    const int tid  = threadIdx.x;
    const int wave = tid >> 6;
    const int lane = tid & 63;
    const int m0 = blockIdx.x * 128;
    const int n0 = blockIdx.y * 128;

    int arow = m0 + (tid >> 1); if (arow > M - 1) arow = M - 1;
    int brow = n0 + (tid >> 1); if (brow > N - 1) brow = N - 1;
    const unsigned short* pa = A + (size_t)arow * K + (tid & 1) * 16;
    const unsigned short* pb = W + (size_t)brow * K + (tid & 1) * 16;
    const int soff = tid * 16;    // shorts; thread covers 32 contiguous bytes

    const int wm = (wave >> 1) * 64;
    const int wn = (wave & 1) * 64;
    const int fr = lane & 15;
    const int fk = (lane >> 4) * 8;

    const int NI = K >> 5;
    f32x4 acc[4][4] = {};

    uint4 ra0, ra1, rb0, rb1;   // set X
    uint4 sa0, sa1, sb0, sb1;   // set Y
    ra0 = *(const uint4*)(pa);     ra1 = *(const uint4*)(pa + 8);
    rb0 = *(const uint4*)(pb);     rb1 = *(const uint4*)(pb + 8);

    auto compute = [&](int buf) {
        bf16x8 af[4], bfv[4];
#pragma unroll
        for (int x = 0; x < 4; ++x)
            af[x] = *(const bf16x8*)&As[buf][(wm + x * 16 + fr) * 32 + fk];
#pragma unroll
        for (int y = 0; y < 4; ++y)
            bfv[y] = *(const bf16x8*)&Bs[buf][(wn + y * 16 + fr) * 32 + fk];
#pragma unroll
        for (int x = 0; x < 4; ++x)
#pragma unroll
            for (int y = 0; y < 4; ++y)
                acc[x][y] = __builtin_amdgcn_mfma_f32_16x16x32_bf16(
                    af[x], bfv[y], acc[x][y], 0, 0, 0);
    };

    for (int i = 0; i < NI; i += 2) {
        {   // issue loads for iter i+1 (always exists: NI even)
            const unsigned short* qa = pa + (size_t)(i + 1) * 32;
            const unsigned short* qb = pb + (size_t)(i + 1) * 32;
            sa0 = *(const uint4*)(qa); sa1 = *(const uint4*)(qa + 8);
            sb0 = *(const uint4*)(qb); sb1 = *(const uint4*)(qb + 8);
        }
        // stage X -> buf0 (auto waits only set-X loads; set-Y stays in flight)
        *(uint4*)&As[0][soff] = ra0; *(uint4*)&As[0][soff + 8] = ra1;
        *(uint4*)&Bs[0][soff] = rb0; *(uint4*)&Bs[0][soff + 8] = rb1;
        WAIT_LGKM0(); BARRIER();
        compute(0);
        BARRIER();
        if (i + 2 < NI) {   // issue loads for iter i+2
            const unsigned short* qa = pa + (size_t)(i + 2) * 32;
            const unsigned short* qb = pb + (size_t)(i + 2) * 32;
            ra0 = *(const uint4*)(qa); ra1 = *(const uint4*)(qa + 8);
            rb0 = *(const uint4*)(qb); rb1 = *(const uint4*)(qb + 8);
        }
        // stage Y -> buf1
        *(uint4*)&As[1][soff] = sa0; *(uint4*)&As[1][soff + 8] = sa1;
        *(uint4*)&Bs[1][soff] = sb0; *(uint4*)&Bs[1][soff + 8] = sb1;
        WAIT_LGKM0(); BARRIER();
        compute(1);
        BARRIER();
    }

    const int quad = lane >> 4;
#pragma unroll
    for (int j = 0; j < 4; ++j) {
        const int col = n0 + wn + j * 16 + fr;
        if (col >= N) continue;
        float bv = 0.f;
        if (bias) bv += bias[col];
        if (bias2 && col < b2lim) bv += bias2[col];
#pragma unroll
        for (int i = 0; i < 4; ++i) {
#pragma unroll
            for (int r = 0; r < 4; ++r) {
                const int row = m0 + wm + i * 16 + quad * 4 + r;
                if (row >= M) continue;
                float v = acc[i][j][r] + bv;
                if (relu) v = fmaxf(v, 0.f);
                if (Cf) Cf[(size_t)row * N + col] = v;
                if (Cb) Cb[(size_t)row * N + col] = f2b(v);
            }
        }
    }
}

// ---------------------------------------------------------------------------
// GEMM (N=256, full row per block) + residual + LayerNorm fused.
// Block = 32 rows x 256 cols; wave w -> cols w*64..+63. Same 2-deep pipeline.
// In-place safe when A rows alias outb rows (block reads only its own rows).
__global__ __launch_bounds__(256) void gemm_ln(
    const unsigned short* __restrict__ A,    // M x K bf16
    const unsigned short* __restrict__ W,    // 256 x K bf16
    const float* __restrict__ bias,          // 256
    const float* __restrict__ resid,         // M x 256 fp32
    const float* __restrict__ g, const float* __restrict__ bb,
    float* __restrict__ outf, unsigned short* __restrict__ outb, int K)
{
    __shared__ __align__(16) unsigned short As[2][1024];   // 32x32 per buf
    __shared__ __align__(16) unsigned short Bs[2][8192];   // 256x32 per buf
    const int tid  = threadIdx.x;
    const int wave = tid >> 6;
    const int lane = tid & 63;
    const int m0 = blockIdx.x * 32;

    const bool doA = (tid < 128);                    // waves 0,1 stage A
    const unsigned short* pa = A + (size_t)(m0 + (tid >> 2)) * K + (tid & 3) * 8;
    // B chunk j covers rows 64j + (tid>>2); LDS offset j*2048 + tid*8 (contig)
    const unsigned short* pb0 = W + (size_t)(tid >> 2) * K + (tid & 3) * 8;
    const unsigned short* pb1 = pb0 + (size_t)64 * K;
    const unsigned short* pb2 = pb0 + (size_t)128 * K;
    const unsigned short* pb3 = pb0 + (size_t)192 * K;
    const int so = tid * 8;

    const int fr = lane & 15;
    const int fk = (lane >> 4) * 8;
    const int quad = lane >> 4;
    const int colbase = wave * 64;
    const int NI = K >> 5;

    f32x4 acc[2][4] = {};
    uint4 ra, rb0, rb1, rb2, rb3;   // set X
    uint4 sa, sb0, sb1, sb2, sb3;   // set Y
    if (doA) ra = *(const uint4*)(pa);
    rb0 = *(const uint4*)(pb0); rb1 = *(const uint4*)(pb1);
    rb2 = *(const uint4*)(pb2); rb3 = *(const uint4*)(pb3);

    auto compute = [&](int buf) {
        bf16x8 af[2], bfv[4];
#pragma unroll
        for (int x = 0; x < 2; ++x)
            af[x] = *(const bf16x8*)&As[buf][(x * 16 + fr) * 32 + fk];
#pragma unroll
        for (int y = 0; y < 4; ++y)
            bfv[y] = *(const bf16x8*)&Bs[buf][(colbase + y * 16 + fr) * 32 + fk];
#pragma unroll
        for (int x = 0; x < 2; ++x)
#pragma unroll
            for (int y = 0; y < 4; ++y)
                acc[x][y] = __builtin_amdgcn_mfma_f32_16x16x32_bf16(
                    af[x], bfv[y], acc[x][y], 0, 0, 0);
    };

    for (int i = 0; i < NI; i += 2) {
        {   // issue i+1 -> Y
            const int k1 = (i + 1) * 32;
            if (doA) sa = *(const uint4*)(pa + k1);
            sb0 = *(const uint4*)(pb0 + k1); sb1 = *(const uint4*)(pb1 + k1);
            sb2 = *(const uint4*)(pb2 + k1); sb3 = *(const uint4*)(pb3 + k1);
        }
        if (doA) *(uint4*)&As[0][so] = ra;
        *(uint4*)&Bs[0][so] = rb0;        *(uint4*)&Bs[0][2048 + so] = rb1;
        *(uint4*)&Bs[0][4096 + so] = rb2; *(uint4*)&Bs[0][6144 + so] = rb3;
        WAIT_LGKM0(); BARRIER();
        compute(0);
        BARRIER();
        if (i + 2 < NI) {   // issue i+2 -> X
            const int k2 = (i + 2) * 32;
            if (doA) ra = *(const uint4*)(pa + k2);
            rb0 = *(const uint4*)(pb0 + k2); rb1 = *(const uint4*)(pb1 + k2);
            rb2 = *(const uint4*)(pb2 + k2); rb3 = *(const uint4*)(pb3 + k2);
        }
        if (doA) *(uint4*)&As[1][so] = sa;
        *(uint4*)&Bs[1][so] = sb0;        *(uint4*)&Bs[1][2048 + so] = sb1;
        *(uint4*)&Bs[1][4096 + so] = sb2; *(uint4*)&Bs[1][6144 + so] = sb3;
        WAIT_LGKM0(); BARRIER();
        compute(1);
        BARRIER();
    }

    // ---- fused epilogue: v = acc + bias + resid; LN over 256 cols ----
    float2* red = (float2*)&As[0][0];   // 128 float2 = 1 KB (post-barrier safe)
    float rs[2][4], rq[2][4];
#pragma unroll
    for (int x = 0; x < 2; ++x) {
#pragma unroll
        for (int r = 0; r < 4; ++r) {
            const int row = m0 + x * 16 + quad * 4 + r;
            float s = 0.f, q = 0.f;
#pragma unroll
            for (int y = 0; y < 4; ++y) {
                const int col = colbase + y * 16 + fr;
                float v = acc[x][y][r] + bias[col] + resid[(size_t)row * 256 + col];
                acc[x][y][r] = v;
                s += v; q += v * v;
            }
            rs[x][r] = s; rq[x][r] = q;
        }
    }
#pragma unroll
    for (int off = 1; off < 16; off <<= 1) {
#pragma unroll
        for (int x = 0; x < 2; ++x)
#pragma unroll
            for (int r = 0; r < 4; ++r) {
                rs[x][r] += __shfl_xor(rs[x][r], off);
                rq[x][r] += __shfl_xor(rq[x][r], off);
            }
    }
    if ((lane & 15) == 0) {
#pragma unroll
        for (int x = 0; x < 2; ++x)
#pragma unroll
            for (int r = 0; r < 4; ++r)
                red[wave * 32 + x * 16 + quad * 4 + r] = make_float2(rs[x][r], rq[x][r]);
    }
    __syncthreads();
#pragma unroll
    for (int x = 0; x < 2; ++x) {
#pragma unroll
        for (int r = 0; r < 4; ++r) {
            const int rl = x * 16 + quad * 4 + r;
            const float2 t0 = red[rl], t1 = red[32 + rl], t2 = red[64 + rl], t3 = red[96 + rl];
            const float sum = t0.x + t1.x + t2.x + t3.x;
            const float sq  = t0.y + t1.y + t2.y + t3.y;
            const float mean = sum * (1.f / 256.f);
            const float var  = sq * (1.f / 256.f) - mean * mean;
            const float inv  = rsqrtf(var + 1e-5f);
            const int row = m0 + rl;
#pragma unroll
            for (int y = 0; y < 4; ++y) {
                const int col = colbase + y * 16 + fr;
                const float val = (acc[x][y][r] - mean) * inv * g[col] + bb[col];
                outf[(size_t)row * 256 + col] = val;
                if (outb) outb[(size_t)row * 256 + col] = f2b(val);
            }
        }
    }
}

// ---------------------------------------------------------------------------
// Self-attention over S=8 (batch axis). Row order (lq,b): row = n*8 + s.
__global__ __launch_bounds__(256) void self_attn_kernel(
    const unsigned short* __restrict__ qkv, unsigned short* __restrict__ ctx)
{
    __shared__ float sh[8][768];
    __shared__ float ls[8][8][8];   // [h][s][t]
    const int n = blockIdx.x;
    const int t = threadIdx.x;
#pragma unroll
    for (int s = 0; s < 8; ++s) {
        const unsigned short* row = qkv + (size_t)(n * 8 + s) * 768;
        sh[s][t]       = b2f(row[t]);
        sh[s][t + 256] = b2f(row[t + 256]);
        sh[s][t + 512] = b2f(row[t + 512]);
    }
    __syncthreads();
    const int h = t >> 5, j = t & 31;
#pragma unroll
    for (int pair = j; pair < 64; pair += 32) {
        const int s = pair >> 3, tt = pair & 7;
        float acc = 0.f;
#pragma unroll
        for (int d = 0; d < 32; ++d)
            acc += sh[s][h * 32 + d] * sh[tt][256 + h * 32 + d];
        ls[h][s][tt] = acc * 0.17677669529663687f;
    }
    __syncthreads();
    if (t < 64) {
        const int hh = t >> 3, s = t & 7;
        float mx = -1e30f;
        for (int tt = 0; tt < 8; ++tt) mx = fmaxf(mx, ls[hh][s][tt]);
        float sum = 0.f;
        for (int tt = 0; tt < 8; ++tt) { float e = expf(ls[hh][s][tt] - mx); ls[hh][s][tt] = e; sum += e; }
        const float inv = 1.f / sum;
        for (int tt = 0; tt < 8; ++tt) ls[hh][s][tt] *= inv;
    }
    __syncthreads();
#pragma unroll
    for (int s = 0; s < 8; ++s) {
        float acc = 0.f;
#pragma unroll
        for (int tt = 0; tt < 8; ++tt)
            acc += ls[h][s][tt] * sh[tt][512 + h * 32 + j];
        ctx[(size_t)(n * 8 + s) * D_MODEL + h * 32 + j] = f2b(acc);
    }
}

// ---------------------------------------------------------------------------
// msprep: one thread per (m,h); softmax + bilinear setup once, packed 12 B/pt,
// written in place over comb rows (whole rows per block; barrier between).
__global__ __launch_bounds__(256) void msprep_kernel(float* __restrict__ comb)
{
    const int tid = threadIdx.x;
    const int m = blockIdx.x * 32 + (tid >> 3);
    const int h = tid & 7;
    const int lq = m >> 3;
    const float* offp = comb + (size_t)m * 288 + h * 24;
    const float* awp  = comb + (size_t)m * 288 + 192 + h * 12;
    float off[24], aw[12];
#pragma unroll
    for (int i = 0; i < 6; ++i) *(float4*)&off[i * 4] = ((const float4*)offp)[i];
#pragma unroll
    for (int i = 0; i < 3; ++i) *(float4*)&aw[i * 4] = ((const float4*)awp)[i];

    float mx = aw[0];
#pragma unroll
    for (int i = 1; i < 12; ++i) mx = fmaxf(mx, aw[i]);
    float se = 0.f;
#pragma unroll
    for (int i = 0; i < 12; ++i) { aw[i] = __expf(aw[i] - mx); se += aw[i]; }
    const float inv = 1.f / se;

    const float refx = ((lq % 60) + 0.5f) * (1.f / 60.f);
    const float refy = ((lq / 60) + 0.5f) * (1.f / 60.f);
    const int HW[3] = {60, 30, 15};
    const int ST[3] = {0, 3600, 4500};

    unsigned int outv[36];
#pragma unroll
    for (int lev = 0; lev < NLEV; ++lev) {
        const int Wl = HW[lev], Hl = HW[lev], s0 = ST[lev];
        const float fWl = (float)Wl, fHl = (float)Hl;
#pragma unroll
        for (int p = 0; p < NPNT; ++p) {
            const int pt = lev * 4 + p;
            const float ox = off[lev * 8 + p * 2];
            const float oy = off[lev * 8 + p * 2 + 1];
            const float px = refx * fWl + ox - 0.5f;
            const float py = refy * fHl + oy - 0.5f;
            const float x0f = floorf(px), y0f = floorf(py);
            const float fx = px - x0f, fy = py - y0f;
            const int x0 = (int)x0f, y0 = (int)y0f;
            const float aww = aw[pt] * inv;
            const float vx0 = (x0 >= 0 && x0 < Wl) ? 1.f : 0.f;
            const float vx1 = (x0 >= -1 && x0 < Wl - 1) ? 1.f : 0.f;
            const float vy0 = (y0 >= 0 && y0 < Hl) ? 1.f : 0.f;
            const float vy1 = (y0 >= -1 && y0 < Hl - 1) ? 1.f : 0.f;
            const int xc0 = min(max(x0, 0), Wl - 1);
            const int xc1 = min(max(x0 + 1, 0), Wl - 1);
            const int yc0 = min(max(y0, 0), Hl - 1);
            const int yc1 = min(max(y0 + 1, 0), Hl - 1);
            const unsigned int sx  = (unsigned int)(xc1 - xc0);
            const unsigned int syW = (unsigned int)((yc1 - yc0) * Wl);
            const unsigned int idx = (unsigned int)(s0 + yc0 * Wl + xc0);
            const float w00 = (1.f - fx) * (1.f - fy) * aww * vx0 * vy0;
            const float w01 = fx * (1.f - fy) * aww * vx1 * vy0;
            const float w10 = (1.f - fx) * fy * aww * vx0 * vy1;
            const float w11 = fx * fy * aww * vx1 * vy1;
            outv[pt * 3]     = idx | (sx << 16) | (syW << 17);
            outv[pt * 3 + 1] = (unsigned int)f2b(w00) | ((unsigned int)f2b(w01) << 16);
            outv[pt * 3 + 2] = (unsigned int)f2b(w10) | ((unsigned int)f2b(w11) << 16);
        }
    }
    __syncthreads();
    uint4* dst = (uint4*)((char*)comb + (size_t)m * 1152 + h * 144);
#pragma unroll
    for (int i = 0; i < 9; ++i) dst[i] = *(uint4*)&outv[i * 4];
}

// ---------------------------------------------------------------------------
// Hot deformable sampling (unchanged).
__global__ __launch_bounds__(256) void msdeform_kernel(
    const unsigned short* __restrict__ value,
    const unsigned int* __restrict__ meta,
    unsigned short* __restrict__ out)
{
    const int bid = blockIdx.x;
    const int b   = bid & 7;
    const int lq0 = (bid >> 3) * 4;
    const int r    = threadIdx.x >> 6;
    const int lane = threadIdx.x & 63;
    const int h = lane >> 3;
    const int l = lane & 7;
    const int m = (lq0 + r) * 8 + b;

    const unsigned int* mp = meta + (size_t)m * 288 + h * 36;
    uint4 md[9];
#pragma unroll
    for (int i = 0; i < 9; ++i) md[i] = ((const uint4*)mp)[i];
    const unsigned int* mw = (const unsigned int*)md;

    const unsigned short* vbase = value + (size_t)b * LIN * 256 + h * 32 + l * 4;

    float a0 = 0.f, a1 = 0.f, a2 = 0.f, a3 = 0.f;
#pragma unroll
    for (int p = 0; p < 12; ++p) {
        const unsigned int pack = mw[p * 3];
        const unsigned int wlo  = mw[p * 3 + 1];
        const unsigned int whi  = mw[p * 3 + 2];
        const unsigned int i00 = pack & 0xFFFFu;
        const unsigned int sx  = (pack >> 16) & 1u;
        const unsigned int syW = pack >> 17;
        const unsigned int i01 = i00 + sx;
        const unsigned int i10 = i00 + syW;
        const unsigned int i11 = i10 + sx;
        const float w00 = __uint_as_float(wlo << 16);
        const float w01 = __uint_as_float(wlo & 0xFFFF0000u);
        const float w10 = __uint_as_float(whi << 16);
        const float w11 = __uint_as_float(whi & 0xFFFF0000u);
        const ushort4 g00 = *(const ushort4*)(vbase + (size_t)i00 * 256);
        const ushort4 g01 = *(const ushort4*)(vbase + (size_t)i01 * 256);
        const ushort4 g10 = *(const ushort4*)(vbase + (size_t)i10 * 256);
        const ushort4 g11 = *(const ushort4*)(vbase + (size_t)i11 * 256);
        a0 += b2f(g00.x) * w00 + b2f(g01.x) * w01 + b2f(g10.x) * w10 + b2f(g11.x) * w11;
        a1 += b2f(g00.y) * w00 + b2f(g01.y) * w01 + b2f(g10.y) * w10 + b2f(g11.y) * w11;
        a2 += b2f(g00.z) * w00 + b2f(g01.z) * w01 + b2f(g10.z) * w10 + b2f(g11.z) * w11;
        a3 += b2f(g00.w) * w00 + b2f(g01.w) * w01 + b2f(g10.w) * w10 + b2f(g11.w) * w11;
    }
    ushort4 o;
    o.x = f2b(a0); o.y = f2b(a1); o.z = f2b(a2); o.w = f2b(a3);
    *(ushort4*)(out + (size_t)m * 256 + h * 32 + l * 4) = o;
}

// ---------------------------------------------------------------------------
extern "C" void kernel_launch(void* const* d_in, const int* in_sizes, int n_in,
                              void* d_out, int out_size, void* d_ws, size_t ws_size,
                              hipStream_t stream)
{
    (void)in_sizes; (void)n_in; (void)out_size; (void)ws_size;
    const float* tgt          = (const float*)d_in[0];   // (LQ,B,D): (lq,b)-major rows
    const float* qp           = (const float*)d_in[1];
    const float* src          = (const float*)d_in[2];
    const float* in_proj_w    = (const float*)d_in[5];
    const float* in_proj_b    = (const float*)d_in[6];
    const float* out_proj_w   = (const float*)d_in[7];
    const float* out_proj_b   = (const float*)d_in[8];
    const float* samp_off_w   = (const float*)d_in[9];
    const float* samp_off_b   = (const float*)d_in[10];
    const float* attn_w_w     = (const float*)d_in[11];
    const float* attn_w_b     = (const float*)d_in[12];
    const float* value_proj_w = (const float*)d_in[13];
    const float* value_proj_b = (const float*)d_in[14];
    const float* cross_out_w  = (const float*)d_in[15];
    const float* cross_out_b  = (const float*)d_in[16];
    const float* ln1_g = (const float*)d_in[17];
    const float* ln1_b = (const float*)d_in[18];
    const float* ln2_g = (const float*)d_in[19];
    const float* ln2_b = (const float*)d_in[20];
    const float* ln3_g = (const float*)d_in[21];
    const float* ln3_b = (const float*)d_in[22];
    const float* ffn_w1 = (const float*)d_in[23];
    const float* ffn_b1 = (const float*)d_in[24];
    const float* ffn_w2 = (const float*)d_in[25];
    const float* ffn_b2 = (const float*)d_in[26];
    float* out = (float*)d_out;

    // ---- fp32 arena (floats) ----
    float* ws    = (float*)d_ws;
    float* t     = ws;                    // LN2 out (residual for LN1)
    float* t2    = ws + 7372800;          // LN1 out (residual for LN3)
    float* comb  = ws + 14745600;         // 28800x288 off+aw -> msprep packed
    float* qpv   = ws + 23040000;         // 1056 qp-proj + 288 cbias
    float* cbias = qpv + 1056;

    // ---- bf16 arena (ushort), after fp32 arena (byte 92,165,376) ----
    unsigned short* bws    = (unsigned short*)((char*)d_ws + 92165376);
    unsigned short* s1     = bws;                  // tgtb -> ctxb -> tb -> t2b
    unsigned short* tgtb   = s1;
    unsigned short* ctxb   = s1;
    unsigned short* tb     = s1;
    unsigned short* t2b    = s1;
    unsigned short* s2     = bws + 7372800;        // qkvb / valueb+msoutb / hiddenb
    unsigned short* qkvb   = s2;
    unsigned short* valueb = s2;
    unsigned short* msoutb = s2 + 9676800;
    unsigned short* hiddenb= s2;
    unsigned short* srcb   = bws + 36864000;
    unsigned short* wtsb   = bws + 46540800;       // 991,232 shorts

    // 1. merged prep (conversions + weight cast + query_pos projections)
    prep_kernel<<<17623, 256, 0, stream>>>(tgt, tgtb, src, srcb,
                                           in_proj_w, out_proj_w, value_proj_w,
                                           cross_out_w, samp_off_w, attn_w_w,
                                           ffn_w1, ffn_w2, wtsb,
                                           qp, samp_off_b, attn_w_b, qpv);
    // 2. QKV projection (Q,K cols get query_pos bias via qpv, cols < 512)
    gemm_bf16<<<dim3(225, 6), 256, 0, stream>>>(tgtb, wtsb + 0, in_proj_b, qpv, 512,
                                                nullptr, qkvb, MROWS, 768, 256, 0);
    // 3. self-attention over batch axis
    self_attn_kernel<<<3600, 256, 0, stream>>>(qkvb, ctxb);
    // 4. t = LN2(tgt + out_proj(ctx))   [fused; in-place ctxb->tb safe]
    gemm_ln<<<900, 256, 0, stream>>>(ctxb, wtsb + 196608, out_proj_b, tgt,
                                     ln2_g, ln2_b, t, tb, 256);
    // 5. value projection (M = 37800)
    gemm_bf16<<<dim3(296, 2), 256, 0, stream>>>(srcb, wtsb + 262144, value_proj_b, nullptr, 0,
                                                nullptr, valueb, BATCH * LIN, 256, 256, 0);
    // 6. fused sampling-offset + attn-weight projection (N = 288)
    gemm_bf16<<<dim3(225, 3), 256, 0, stream>>>(tb, wtsb + 393216, cbias, nullptr, 0,
                                                comb, nullptr, MROWS, 288, 256, 0);
    // 7. packed sampling metadata (in place over comb)
    msprep_kernel<<<900, 256, 0, stream>>>(comb);
    // 8. deformable sampling (hot)
    msdeform_kernel<<<7200, 256, 0, stream>>>(valueb, (const unsigned int*)comb, msoutb);
    // 9. t2 = LN1(t + cross_out(msout))   [fused]
    gemm_ln<<<900, 256, 0, stream>>>(msoutb, wtsb + 327680, cross_out_b, t,
                                     ln1_g, ln1_b, t2, t2b, 256);
    // 10. FFN layer 1 (+ReLU), bf16 out
    gemm_bf16<<<dim3(225, 8), 256, 0, stream>>>(t2b, wtsb + 466944, ffn_b1, nullptr, 0,
                                                nullptr, hiddenb, MROWS, DFF, 256, 1);
    // 11. out = LN3(t2 + ffn2(hidden))   [fused; K=1024]
    gemm_ln<<<900, 256, 0, stream>>>(hiddenb, wtsb + 729088, ffn_b2, t2,
                                     ln3_g, ln3_b, out, nullptr, 1024);
}

// Round 7
// 486.851 us; speedup vs baseline: 1.0543x; 1.0543x over previous
//
#include <hip/hip_runtime.h>
#include <hip/hip_bf16.h>
#include <cstddef>
#include <cstdint>

// Problem constants
#define D_MODEL 256
#define NHEAD   8
#define HDIM    32
#define NLEV    3
#define NPNT    4
#define DFF     1024
#define BATCH   8
#define LQ      3600
#define LIN     4725   // 60*60 + 30*30 + 15*15
#define MROWS   (BATCH*LQ)   // 28800; row order is (lq,b): m = lq*8 + b

typedef short bf16x8 __attribute__((ext_vector_type(8)));
typedef float f32x4  __attribute__((ext_vector_type(4)));

__device__ __forceinline__ unsigned short f2b(float x) {
    unsigned int u = __float_as_uint(x);
    unsigned int r = (u + 0x7fffu + ((u >> 16) & 1u)) >> 16;   // RNE
    return (unsigned short)r;
}
__device__ __forceinline__ float b2f(unsigned short s) {
    return __uint_as_float(((unsigned int)s) << 16);
}

#define GLDS16(g, l) __builtin_amdgcn_global_load_lds( \
    (const __attribute__((address_space(1))) void*)(g), \
    (__attribute__((address_space(3))) void*)(l), 16, 0, 0)

// ---------------------------------------------------------------------------
// Merged prep: [0,7200) conv tgt->bf16; [7200,16650) conv src->bf16;
// [16650,17618) weight convert; [17618,17623) query_pos projections.
#define WTOT 991232
__global__ __launch_bounds__(256) void prep_kernel(
    const float* __restrict__ tgt, unsigned short* __restrict__ tgtb,
    const float* __restrict__ srcf, unsigned short* __restrict__ srcb,
    const float* __restrict__ w_in, const float* __restrict__ w_out,
    const float* __restrict__ w_val, const float* __restrict__ w_cross,
    const float* __restrict__ w_so, const float* __restrict__ w_aw,
    const float* __restrict__ w_f1, const float* __restrict__ w_f2,
    unsigned short* __restrict__ wdst,
    const float* __restrict__ qp, const float* __restrict__ so_b,
    const float* __restrict__ aw_b, float* __restrict__ qpv)
{
    const int bid = blockIdx.x;
    const int tid = threadIdx.x;
    if (bid < 7200) {
        int i = bid * 256 + tid;
        float4 v = ((const float4*)tgt)[i];
        ushort4 o; o.x = f2b(v.x); o.y = f2b(v.y); o.z = f2b(v.z); o.w = f2b(v.w);
        ((ushort4*)tgtb)[i] = o;
    } else if (bid < 16650) {
        int i = (bid - 7200) * 256 + tid;
        float4 v = ((const float4*)srcf)[i];
        ushort4 o; o.x = f2b(v.x); o.y = f2b(v.y); o.z = f2b(v.z); o.w = f2b(v.w);
        ((ushort4*)srcb)[i] = o;
    } else if (bid < 17618) {
        int idx = ((bid - 16650) * 256 + tid) * 4;
        if (idx >= WTOT) return;
        const float* src; int off;
        if      (idx < 196608) { src = w_in;    off = idx; }
        else if (idx < 262144) { src = w_out;   off = idx - 196608; }
        else if (idx < 327680) { src = w_val;   off = idx - 262144; }
        else if (idx < 393216) { src = w_cross; off = idx - 327680; }
        else if (idx < 442368) { src = w_so;    off = idx - 393216; }
        else if (idx < 466944) { src = w_aw;    off = idx - 442368; }
        else if (idx < 729088) { src = w_f1;    off = idx - 466944; }
        else                   { src = w_f2;    off = idx - 729088; }
        float4 v = *(const float4*)(src + off);
        ushort4 o; o.x = f2b(v.x); o.y = f2b(v.y); o.z = f2b(v.z); o.w = f2b(v.w);
        *(ushort4*)(wdst + idx) = o;
    } else {
        int o = (bid - 17618) * 256 + tid;
        if (o >= 768 + 192 + 96) return;
        const float* wrow;
        if (o < 768)       wrow = w_in + (size_t)o * D_MODEL;
        else if (o < 960)  wrow = w_so + (size_t)(o - 768) * D_MODEL;
        else               wrow = w_aw + (size_t)(o - 960) * D_MODEL;
        float acc = 0.f;
        for (int d = 0; d < D_MODEL; ++d) acc += qp[d] * wrow[d];
        qpv[o] = acc;
        if (o >= 768) {
            float bias = (o < 960) ? so_b[o - 768] : aw_b[o - 960];
            qpv[1056 + (o - 768)] = acc + bias;
        }
    }
}

// ---------------------------------------------------------------------------
// bf16 MFMA GEMM (R4 proven version): 128x128 tile, BK=64 (2x32 panels),
// global_load_lds width=16 staging.
__global__ __launch_bounds__(256) void gemm_bf16(
    const unsigned short* __restrict__ A,
    const unsigned short* __restrict__ W,
    const float* __restrict__ bias,
    const float* __restrict__ bias2, int b2lim,
    float* __restrict__ Cf, unsigned short* __restrict__ Cb,
    int M, int N, int K, int relu)
{
    __shared__ __align__(16) unsigned short As[2 * 128 * 32];   // 16 KB
    __shared__ __align__(16) unsigned short Bs[2 * 128 * 32];   // 16 KB
    const int tid  = threadIdx.x;
    const int wave = tid >> 6;
    const int lane = tid & 63;
    const int m0 = blockIdx.x * 128;
    const int n0 = blockIdx.y * 128;

    const int lr  = lane >> 2;
    const int lc8 = (lane & 3) * 8;
    int ar0 = m0 + wave * 32 + lr;      if (ar0 > M - 1) ar0 = M - 1;
    int ar1 = m0 + wave * 32 + 16 + lr; if (ar1 > M - 1) ar1 = M - 1;
    int br0 = n0 + wave * 32 + lr;      if (br0 > N - 1) br0 = N - 1;
    int br1 = n0 + wave * 32 + 16 + lr; if (br1 > N - 1) br1 = N - 1;
    const unsigned short* pa0 = A + (size_t)ar0 * K + lc8;
    const unsigned short* pa1 = A + (size_t)ar1 * K + lc8;
    const unsigned short* pb0 = W + (size_t)br0 * K + lc8;
    const unsigned short* pb1 = W + (size_t)br1 * K + lc8;
    unsigned short* la0 = As + wave * 1024;
    unsigned short* la1 = As + wave * 1024 + 512;
    unsigned short* lb0 = Bs + wave * 1024;
    unsigned short* lb1 = Bs + wave * 1024 + 512;

    const int wm = (wave >> 1) * 64;
    const int wn = (wave & 1) * 64;
    const int fr = lane & 15;
    const int fk = (lane >> 4) * 8;

    f32x4 acc[4][4] = {};

    for (int k0 = 0; k0 < K; k0 += 64) {
        GLDS16(pa0, la0); GLDS16(pa0 + 32, la0 + 4096);
        GLDS16(pa1, la1); GLDS16(pa1 + 32, la1 + 4096);
        GLDS16(pb0, lb0); GLDS16(pb0 + 32, lb0 + 4096);
        GLDS16(pb1, lb1); GLDS16(pb1 + 32, lb1 + 4096);
        pa0 += 64; pa1 += 64; pb0 += 64; pb1 += 64;
        __syncthreads();
#pragma unroll
        for (int p = 0; p < 2; ++p) {
            bf16x8 af[4], bfv[4];
#pragma unroll
            for (int i = 0; i < 4; ++i)
                af[i] = *(const bf16x8*)&As[p * 4096 + (wm + i * 16 + fr) * 32 + fk];
#pragma unroll
            for (int j = 0; j < 4; ++j)
                bfv[j] = *(const bf16x8*)&Bs[p * 4096 + (wn + j * 16 + fr) * 32 + fk];
#pragma unroll
            for (int i = 0; i < 4; ++i)
#pragma unroll
                for (int j = 0; j < 4; ++j)
                    acc[i][j] = __builtin_amdgcn_mfma_f32_16x16x32_bf16(
                        af[i], bfv[j], acc[i][j], 0, 0, 0);
        }
        __syncthreads();
    }

    const int quad = lane >> 4;
#pragma unroll
    for (int j = 0; j < 4; ++j) {
        const int col = n0 + wn + j * 16 + fr;
        if (col >= N) continue;
        float bv = 0.f;
        if (bias) bv += bias[col];
        if (bias2 && col < b2lim) bv += bias2[col];
#pragma unroll
        for (int i = 0; i < 4; ++i) {
#pragma unroll
            for (int r = 0; r < 4; ++r) {
                const int row = m0 + wm + i * 16 + quad * 4 + r;
                if (row >= M) continue;
                float v = acc[i][j][r] + bv;
                if (relu) v = fmaxf(v, 0.f);
                if (Cf) Cf[(size_t)row * N + col] = v;
                if (Cb) Cb[(size_t)row * N + col] = f2b(v);
            }
        }
    }
}

// ---------------------------------------------------------------------------
// GEMM (N=256, full row per block) + residual + LayerNorm fused (R4 proven).
// Block = 64 rows x 256 cols; wave w computes cols w*64..+63 of all rows.
__global__ __launch_bounds__(256) void gemm_ln(
    const unsigned short* __restrict__ A,    // M x K bf16
    const unsigned short* __restrict__ W,    // 256 x K bf16
    const float* __restrict__ bias,          // 256
    const float* __restrict__ resid,         // M x 256 fp32
    const float* __restrict__ g, const float* __restrict__ bb,
    float* __restrict__ outf, unsigned short* __restrict__ outb, int K)
{
    __shared__ __align__(16) unsigned short As[2 * 64 * 32];    // 8 KB
    __shared__ __align__(16) unsigned short Bs[2 * 256 * 32];   // 32 KB
    const int tid  = threadIdx.x;
    const int wave = tid >> 6;
    const int lane = tid & 63;
    const int m0 = blockIdx.x * 64;

    const int arow = tid >> 2;
    const int akc  = (tid & 3) * 8;
    const unsigned short* pa = A + (size_t)(m0 + arow) * K + akc;
    unsigned short* la = As + tid * 8;
    const unsigned short* pb0 = W + (size_t)(arow)       * K + akc;
    const unsigned short* pb1 = W + (size_t)(64  + arow) * K + akc;
    const unsigned short* pb2 = W + (size_t)(128 + arow) * K + akc;
    const unsigned short* pb3 = W + (size_t)(192 + arow) * K + akc;
    unsigned short* lb0 = Bs + tid * 8;
    unsigned short* lb1 = Bs + 2048 + tid * 8;
    unsigned short* lb2 = Bs + 4096 + tid * 8;
    unsigned short* lb3 = Bs + 6144 + tid * 8;

    const int fr = lane & 15;
    const int fk = (lane >> 4) * 8;
    const int quad = lane >> 4;
    const int colbase = wave * 64;

    f32x4 acc[4][4] = {};

    for (int k0 = 0; k0 < K; k0 += 64) {
        GLDS16(pa, la);        GLDS16(pa + 32, la + 2048);
        GLDS16(pb0, lb0);      GLDS16(pb0 + 32, lb0 + 8192);
        GLDS16(pb1, lb1);      GLDS16(pb1 + 32, lb1 + 8192);
        GLDS16(pb2, lb2);      GLDS16(pb2 + 32, lb2 + 8192);
        GLDS16(pb3, lb3);      GLDS16(pb3 + 32, lb3 + 8192);
        pa += 64; pb0 += 64; pb1 += 64; pb2 += 64; pb3 += 64;
        __syncthreads();
#pragma unroll
        for (int p = 0; p < 2; ++p) {
            bf16x8 af[4], bfv[4];
#pragma unroll
            for (int i = 0; i < 4; ++i)
                af[i] = *(const bf16x8*)&As[p * 2048 + (i * 16 + fr) * 32 + fk];
#pragma unroll
            for (int j = 0; j < 4; ++j)
                bfv[j] = *(const bf16x8*)&Bs[p * 8192 + (colbase + j * 16 + fr) * 32 + fk];
#pragma unroll
            for (int i = 0; i < 4; ++i)
#pragma unroll
                for (int j = 0; j < 4; ++j)
                    acc[i][j] = __builtin_amdgcn_mfma_f32_16x16x32_bf16(
                        af[i], bfv[j], acc[i][j], 0, 0, 0);
        }
        __syncthreads();
    }

    // ---- fused epilogue: v = acc + bias + resid; LN over 256 cols ----
    float2* red = (float2*)As;   // 256 entries, aliases As (post-barrier safe)
    float rs[4][4], rq[4][4];
#pragma unroll
    for (int i = 0; i < 4; ++i) {
#pragma unroll
        for (int r = 0; r < 4; ++r) {
            const int row = m0 + i * 16 + quad * 4 + r;
            float s = 0.f, q = 0.f;
#pragma unroll
            for (int j = 0; j < 4; ++j) {
                const int col = colbase + j * 16 + fr;
                float v = acc[i][j][r] + bias[col] + resid[(size_t)row * 256 + col];
                acc[i][j][r] = v;
                s += v; q += v * v;
            }
            rs[i][r] = s; rq[i][r] = q;
        }
    }
#pragma unroll
    for (int off = 1; off < 16; off <<= 1) {
#pragma unroll
        for (int i = 0; i < 4; ++i)
#pragma unroll
            for (int r = 0; r < 4; ++r) {
                rs[i][r] += __shfl_xor(rs[i][r], off);
                rq[i][r] += __shfl_xor(rq[i][r], off);
            }
    }
    if ((lane & 15) == 0) {
#pragma unroll
        for (int i = 0; i < 4; ++i)
#pragma unroll
            for (int r = 0; r < 4; ++r)
                red[wave * 64 + i * 16 + quad * 4 + r] = make_float2(rs[i][r], rq[i][r]);
    }
    __syncthreads();
#pragma unroll
    for (int i = 0; i < 4; ++i) {
#pragma unroll
        for (int r = 0; r < 4; ++r) {
            const int rl = i * 16 + quad * 4 + r;
            const float2 t0 = red[rl], t1 = red[64 + rl], t2 = red[128 + rl], t3 = red[192 + rl];
            const float sum = t0.x + t1.x + t2.x + t3.x;
            const float sq  = t0.y + t1.y + t2.y + t3.y;
            const float mean = sum * (1.f / 256.f);
            const float var  = sq * (1.f / 256.f) - mean * mean;
            const float inv  = rsqrtf(var + 1e-5f);
            const int row = m0 + rl;
#pragma unroll
            for (int j = 0; j < 4; ++j) {
                const int col = colbase + j * 16 + fr;
                const float val = (acc[i][j][r] - mean) * inv * g[col] + bb[col];
                outf[(size_t)row * 256 + col] = val;
                if (outb) outb[(size_t)row * 256 + col] = f2b(val);
            }
        }
    }
}

// ---------------------------------------------------------------------------
// Fully fused FFN: out = LN3(resid + W2 @ relu(W1 @ a + b1) + b2).
// Block = 32 rows x 256 out cols; 16 chunks of 64 hidden units; hidden tile
// lives only in LDS (bf16). Weights stream from L2 (1 MB total, shared).
// LDS = A 16K + Wc 32K + hid 4K + red 1K = 53 KB -> 3 blocks/CU.
// Staging maps (1 wave-load = 1 KB = 2 rows of 512 B):
//   A : 16 chunks, chunk c = rows {2c,2c+1} -> Ab + c*512   (dense [row][256])
//   W1: 32 chunks, chunk c = rows {2c,2c+1} -> Wc + c*512   (dense [row][256])
//   W2: 32 chunks, chunk c = rows 8c..8c+7, 64-wide k-slice -> Wc + c*512
//       (dense [row][64])
__global__ __launch_bounds__(256) void ffn_fused_kernel(
    const unsigned short* __restrict__ A,     // M x 256 bf16 (t2b)
    const unsigned short* __restrict__ W1,    // 1024 x 256 bf16
    const float* __restrict__ b1,             // 1024
    const unsigned short* __restrict__ W2,    // 256 x 1024 bf16
    const float* __restrict__ b2,             // 256
    const float* __restrict__ resid,          // M x 256 fp32 (t2)
    const float* __restrict__ g, const float* __restrict__ bb,
    float* __restrict__ outf)
{
    __shared__ __align__(16) unsigned short Ab[8192];    // 32 x 256
    __shared__ __align__(16) unsigned short Wc[16384];   // W1c 64x256 / W2c 256x64
    __shared__ __align__(16) unsigned short hid[2048];   // 32 x 64
    __shared__ float2 red[128];
    const int tid  = threadIdx.x;
    const int wave = tid >> 6;
    const int lane = tid & 63;
    const int m0 = blockIdx.x * 32;
    const int fr   = lane & 15;
    const int quad = lane >> 4;
    const int fk   = quad * 8;

    // stage A (32x256): 16 wave-loads of 1 KB, 2 rows each (FIXED map)
#pragma unroll
    for (int j = 0; j < 4; ++j) {
        const int c = wave * 4 + j;          // 0..15, rows {2c, 2c+1}
        GLDS16(A + (size_t)(m0 + c * 2 + (lane >> 5)) * 256 + (lane & 31) * 8,
               Ab + c * 512);
    }
    __syncthreads();
    bf16x8 af[2][8];
#pragma unroll
    for (int i = 0; i < 2; ++i)
#pragma unroll
        for (int s = 0; s < 8; ++s)
            af[i][s] = *(const bf16x8*)&Ab[(i * 16 + fr) * 256 + s * 32 + fk];

    f32x4 acc2[2][4] = {};

    for (int h = 0; h < 16; ++h) {
        __syncthreads();   // Wc free (prior gemm2 reads done)
        // stage W1 chunk: rows [64h, 64h+64)
#pragma unroll
        for (int j = 0; j < 8; ++j) {
            const int c = wave * 8 + j;      // 0..31, rows {2c, 2c+1} of chunk
            GLDS16(W1 + (size_t)(h * 64 + c * 2 + (lane >> 5)) * 256 + (lane & 31) * 8,
                   Wc + c * 512);
        }
        __syncthreads();
        // gemm1: wave w -> hidden cols [16w, 16w+16)
        f32x4 acc1[2] = {};
#pragma unroll
        for (int s = 0; s < 8; ++s) {
            bf16x8 bv = *(const bf16x8*)&Wc[(wave * 16 + fr) * 256 + s * 32 + fk];
            acc1[0] = __builtin_amdgcn_mfma_f32_16x16x32_bf16(af[0][s], bv, acc1[0], 0, 0, 0);
            acc1[1] = __builtin_amdgcn_mfma_f32_16x16x32_bf16(af[1][s], bv, acc1[1], 0, 0, 0);
        }
        const float bias1 = b1[h * 64 + wave * 16 + fr];
#pragma unroll
        for (int i = 0; i < 2; ++i)
#pragma unroll
            for (int r = 0; r < 4; ++r) {
                float v = fmaxf(acc1[i][r] + bias1, 0.f);
                hid[(i * 16 + quad * 4 + r) * 64 + wave * 16 + fr] = f2b(v);
            }
        __syncthreads();   // hid ready; Wc reads done
        // stage W2 chunk: 256 rows x k[64h, 64h+64), 128 B per row
#pragma unroll
        for (int j = 0; j < 8; ++j) {
            const int c = wave * 8 + j;      // 0..31, rows 8c..8c+7
            GLDS16(W2 + (size_t)(c * 8 + (lane >> 3)) * 1024 + h * 64 + (lane & 7) * 8,
                   Wc + c * 512);
        }
        __syncthreads();
        // gemm2: wave w -> out cols [64w, 64w+64); k = 64 (2 steps)
#pragma unroll
        for (int s = 0; s < 2; ++s) {
            bf16x8 a2[2], b2v[4];
#pragma unroll
            for (int i = 0; i < 2; ++i)
                a2[i] = *(const bf16x8*)&hid[(i * 16 + fr) * 64 + s * 32 + fk];
#pragma unroll
            for (int j2 = 0; j2 < 4; ++j2)
                b2v[j2] = *(const bf16x8*)&Wc[(wave * 64 + j2 * 16 + fr) * 64 + s * 32 + fk];
#pragma unroll
            for (int i = 0; i < 2; ++i)
#pragma unroll
                for (int j2 = 0; j2 < 4; ++j2)
                    acc2[i][j2] = __builtin_amdgcn_mfma_f32_16x16x32_bf16(
                        a2[i], b2v[j2], acc2[i][j2], 0, 0, 0);
        }
    }

    // ---- epilogue: v = acc2 + b2 + resid; LN over 256 cols ----
    const int colbase = wave * 64;
    float rs[2][4], rq[2][4];
#pragma unroll
    for (int x = 0; x < 2; ++x) {
#pragma unroll
        for (int r = 0; r < 4; ++r) {
            const int row = m0 + x * 16 + quad * 4 + r;
            float s = 0.f, q = 0.f;
#pragma unroll
            for (int y = 0; y < 4; ++y) {
                const int col = colbase + y * 16 + fr;
                float v = acc2[x][y][r] + b2[col] + resid[(size_t)row * 256 + col];
                acc2[x][y][r] = v;
                s += v; q += v * v;
            }
            rs[x][r] = s; rq[x][r] = q;
        }
    }
#pragma unroll
    for (int off = 1; off < 16; off <<= 1) {
#pragma unroll
        for (int x = 0; x < 2; ++x)
#pragma unroll
            for (int r = 0; r < 4; ++r) {
                rs[x][r] += __shfl_xor(rs[x][r], off);
                rq[x][r] += __shfl_xor(rq[x][r], off);
            }
    }
    if ((lane & 15) == 0) {
#pragma unroll
        for (int x = 0; x < 2; ++x)
#pragma unroll
            for (int r = 0; r < 4; ++r)
                red[wave * 32 + x * 16 + quad * 4 + r] = make_float2(rs[x][r], rq[x][r]);
    }
    __syncthreads();
#pragma unroll
    for (int x = 0; x < 2; ++x) {
#pragma unroll
        for (int r = 0; r < 4; ++r) {
            const int rl = x * 16 + quad * 4 + r;
            const float2 t0 = red[rl], t1 = red[32 + rl], t2 = red[64 + rl], t3 = red[96 + rl];
            const float sum = t0.x + t1.x + t2.x + t3.x;
            const float sq  = t0.y + t1.y + t2.y + t3.y;
            const float mean = sum * (1.f / 256.f);
            const float var  = sq * (1.f / 256.f) - mean * mean;
            const float inv  = rsqrtf(var + 1e-5f);
            const int row = m0 + rl;
#pragma unroll
            for (int y = 0; y < 4; ++y) {
                const int col = colbase + y * 16 + fr;
                outf[(size_t)row * 256 + col] = (acc2[x][y][r] - mean) * inv * g[col] + bb[col];
            }
        }
    }
}

// ---------------------------------------------------------------------------
// Self-attention over S=8 (batch axis). Row order (lq,b): row = n*8 + s.
__global__ __launch_bounds__(256) void self_attn_kernel(
    const unsigned short* __restrict__ qkv, unsigned short* __restrict__ ctx)
{
    __shared__ float sh[8][768];
    __shared__ float ls[8][8][8];   // [h][s][t]
    const int n = blockIdx.x;
    const int t = threadIdx.x;
#pragma unroll
    for (int s = 0; s < 8; ++s) {
        const unsigned short* row = qkv + (size_t)(n * 8 + s) * 768;
        sh[s][t]       = b2f(row[t]);
        sh[s][t + 256] = b2f(row[t + 256]);
        sh[s][t + 512] = b2f(row[t + 512]);
    }
    __syncthreads();
    const int h = t >> 5, j = t & 31;
#pragma unroll
    for (int pair = j; pair < 64; pair += 32) {
        const int s = pair >> 3, tt = pair & 7;
        float acc = 0.f;
#pragma unroll
        for (int d = 0; d < 32; ++d)
            acc += sh[s][h * 32 + d] * sh[tt][256 + h * 32 + d];
        ls[h][s][tt] = acc * 0.17677669529663687f;
    }
    __syncthreads();
    if (t < 64) {
        const int hh = t >> 3, s = t & 7;
        float mx = -1e30f;
        for (int tt = 0; tt < 8; ++tt) mx = fmaxf(mx, ls[hh][s][tt]);
        float sum = 0.f;
        for (int tt = 0; tt < 8; ++tt) { float e = expf(ls[hh][s][tt] - mx); ls[hh][s][tt] = e; sum += e; }
        const float inv = 1.f / sum;
        for (int tt = 0; tt < 8; ++tt) ls[hh][s][tt] *= inv;
    }
    __syncthreads();
#pragma unroll
    for (int s = 0; s < 8; ++s) {
        float acc = 0.f;
#pragma unroll
        for (int tt = 0; tt < 8; ++tt)
            acc += ls[h][s][tt] * sh[tt][512 + h * 32 + j];
        ctx[(size_t)(n * 8 + s) * D_MODEL + h * 32 + j] = f2b(acc);
    }
}

// ---------------------------------------------------------------------------
// msprep: one thread per (m,h); softmax + bilinear setup once, packed 12 B/pt,
// written in place over comb rows (whole rows per block; barrier between).
__global__ __launch_bounds__(256) void msprep_kernel(float* __restrict__ comb)
{
    const int tid = threadIdx.x;
    const int m = blockIdx.x * 32 + (tid >> 3);
    const int h = tid & 7;
    const int lq = m >> 3;
    const float* offp = comb + (size_t)m * 288 + h * 24;
    const float* awp  = comb + (size_t)m * 288 + 192 + h * 12;
    float off[24], aw[12];
#pragma unroll
    for (int i = 0; i < 6; ++i) *(float4*)&off[i * 4] = ((const float4*)offp)[i];
#pragma unroll
    for (int i = 0; i < 3; ++i) *(float4*)&aw[i * 4] = ((const float4*)awp)[i];

    float mx = aw[0];
#pragma unroll
    for (int i = 1; i < 12; ++i) mx = fmaxf(mx, aw[i]);
    float se = 0.f;
#pragma unroll
    for (int i = 0; i < 12; ++i) { aw[i] = __expf(aw[i] - mx); se += aw[i]; }
    const float inv = 1.f / se;

    const float refx = ((lq % 60) + 0.5f) * (1.f / 60.f);
    const float refy = ((lq / 60) + 0.5f) * (1.f / 60.f);
    const int HW[3] = {60, 30, 15};
    const int ST[3] = {0, 3600, 4500};

    unsigned int outv[36];
#pragma unroll
    for (int lev = 0; lev < NLEV; ++lev) {
        const int Wl = HW[lev], Hl = HW[lev], s0 = ST[lev];
        const float fWl = (float)Wl, fHl = (float)Hl;
#pragma unroll
        for (int p = 0; p < NPNT; ++p) {
            const int pt = lev * 4 + p;
            const float ox = off[lev * 8 + p * 2];
            const float oy = off[lev * 8 + p * 2 + 1];
            const float px = refx * fWl + ox - 0.5f;
            const float py = refy * fHl + oy - 0.5f;
            const float x0f = floorf(px), y0f = floorf(py);
            const float fx = px - x0f, fy = py - y0f;
            const int x0 = (int)x0f, y0 = (int)y0f;
            const float aww = aw[pt] * inv;
            const float vx0 = (x0 >= 0 && x0 < Wl) ? 1.f : 0.f;
            const float vx1 = (x0 >= -1 && x0 < Wl - 1) ? 1.f : 0.f;
            const float vy0 = (y0 >= 0 && y0 < Hl) ? 1.f : 0.f;
            const float vy1 = (y0 >= -1 && y0 < Hl - 1) ? 1.f : 0.f;
            const int xc0 = min(max(x0, 0), Wl - 1);
            const int xc1 = min(max(x0 + 1, 0), Wl - 1);
            const int yc0 = min(max(y0, 0), Hl - 1);
            const int yc1 = min(max(y0 + 1, 0), Hl - 1);
            const unsigned int sx  = (unsigned int)(xc1 - xc0);
            const unsigned int syW = (unsigned int)((yc1 - yc0) * Wl);
            const unsigned int idx = (unsigned int)(s0 + yc0 * Wl + xc0);
            const float w00 = (1.f - fx) * (1.f - fy) * aww * vx0 * vy0;
            const float w01 = fx * (1.f - fy) * aww * vx1 * vy0;
            const float w10 = (1.f - fx) * fy * aww * vx0 * vy1;
            const float w11 = fx * fy * aww * vx1 * vy1;
            outv[pt * 3]     = idx | (sx << 16) | (syW << 17);
            outv[pt * 3 + 1] = (unsigned int)f2b(w00) | ((unsigned int)f2b(w01) << 16);
            outv[pt * 3 + 2] = (unsigned int)f2b(w10) | ((unsigned int)f2b(w11) << 16);
        }
    }
    __syncthreads();
    uint4* dst = (uint4*)((char*)comb + (size_t)m * 1152 + h * 144);
#pragma unroll
    for (int i = 0; i < 9; ++i) dst[i] = *(uint4*)&outv[i * 4];
}

// ---------------------------------------------------------------------------
// Hot deformable sampling (unchanged).
__global__ __launch_bounds__(256) void msdeform_kernel(
    const unsigned short* __restrict__ value,
    const unsigned int* __restrict__ meta,
    unsigned short* __restrict__ out)
{
    const int bid = blockIdx.x;
    const int b   = bid & 7;
    const int lq0 = (bid >> 3) * 4;
    const int r    = threadIdx.x >> 6;
    const int lane = threadIdx.x & 63;
    const int h = lane >> 3;
    const int l = lane & 7;
    const int m = (lq0 + r) * 8 + b;

    const unsigned int* mp = meta + (size_t)m * 288 + h * 36;
    uint4 md[9];
#pragma unroll
    for (int i = 0; i < 9; ++i) md[i] = ((const uint4*)mp)[i];
    const unsigned int* mw = (const unsigned int*)md;

    const unsigned short* vbase = value + (size_t)b * LIN * 256 + h * 32 + l * 4;

    float a0 = 0.f, a1 = 0.f, a2 = 0.f, a3 = 0.f;
#pragma unroll
    for (int p = 0; p < 12; ++p) {
        const unsigned int pack = mw[p * 3];
        const unsigned int wlo  = mw[p * 3 + 1];
        const unsigned int whi  = mw[p * 3 + 2];
        const unsigned int i00 = pack & 0xFFFFu;
        const unsigned int sx  = (pack >> 16) & 1u;
        const unsigned int syW = pack >> 17;
        const unsigned int i01 = i00 + sx;
        const unsigned int i10 = i00 + syW;
        const unsigned int i11 = i10 + sx;
        const float w00 = __uint_as_float(wlo << 16);
        const float w01 = __uint_as_float(wlo & 0xFFFF0000u);
        const float w10 = __uint_as_float(whi << 16);
        const float w11 = __uint_as_float(whi & 0xFFFF0000u);
        const ushort4 g00 = *(const ushort4*)(vbase + (size_t)i00 * 256);
        const ushort4 g01 = *(const ushort4*)(vbase + (size_t)i01 * 256);
        const ushort4 g10 = *(const ushort4*)(vbase + (size_t)i10 * 256);
        const ushort4 g11 = *(const ushort4*)(vbase + (size_t)i11 * 256);
        a0 += b2f(g00.x) * w00 + b2f(g01.x) * w01 + b2f(g10.x) * w10 + b2f(g11.x) * w11;
        a1 += b2f(g00.y) * w00 + b2f(g01.y) * w01 + b2f(g10.y) * w10 + b2f(g11.y) * w11;
        a2 += b2f(g00.z) * w00 + b2f(g01.z) * w01 + b2f(g10.z) * w10 + b2f(g11.z) * w11;
        a3 += b2f(g00.w) * w00 + b2f(g01.w) * w01 + b2f(g10.w) * w10 + b2f(g11.w) * w11;
    }
    ushort4 o;
    o.x = f2b(a0); o.y = f2b(a1); o.z = f2b(a2); o.w = f2b(a3);
    *(ushort4*)(out + (size_t)m * 256 + h * 32 + l * 4) = o;
}

// ---------------------------------------------------------------------------
extern "C" void kernel_launch(void* const* d_in, const int* in_sizes, int n_in,
                              void* d_out, int out_size, void* d_ws, size_t ws_size,
                              hipStream_t stream)
{
    (void)in_sizes; (void)n_in; (void)out_size; (void)ws_size;
    const float* tgt          = (const float*)d_in[0];   // (LQ,B,D): (lq,b)-major rows
    const float* qp           = (const float*)d_in[1];
    const float* src          = (const float*)d_in[2];
    const float* in_proj_w    = (const float*)d_in[5];
    const float* in_proj_b    = (const float*)d_in[6];
    const float* out_proj_w   = (const float*)d_in[7];
    const float* out_proj_b   = (const float*)d_in[8];
    const float* samp_off_w   = (const float*)d_in[9];
    const float* samp_off_b   = (const float*)d_in[10];
    const float* attn_w_w     = (const float*)d_in[11];
    const float* attn_w_b     = (const float*)d_in[12];
    const float* value_proj_w = (const float*)d_in[13];
    const float* value_proj_b = (const float*)d_in[14];
    const float* cross_out_w  = (const float*)d_in[15];
    const float* cross_out_b  = (const float*)d_in[16];
    const float* ln1_g = (const float*)d_in[17];
    const float* ln1_b = (const float*)d_in[18];
    const float* ln2_g = (const float*)d_in[19];
    const float* ln2_b = (const float*)d_in[20];
    const float* ln3_g = (const float*)d_in[21];
    const float* ln3_b = (const float*)d_in[22];
    const float* ffn_w1 = (const float*)d_in[23];
    const float* ffn_b1 = (const float*)d_in[24];
    const float* ffn_w2 = (const float*)d_in[25];
    const float* ffn_b2 = (const float*)d_in[26];
    float* out = (float*)d_out;

    // ---- fp32 arena (floats) ----
    float* ws    = (float*)d_ws;
    float* t     = ws;                    // LN2 out (residual for LN1)
    float* t2    = ws + 7372800;          // LN1 out (residual for LN3)
    float* comb  = ws + 14745600;         // 28800x288 off+aw -> msprep packed
    float* qpv   = ws + 23040000;         // 1056 qp-proj + 288 cbias
    float* cbias = qpv + 1056;

    // ---- bf16 arena (ushort), after fp32 arena (byte 92,165,376) ----
    unsigned short* bws    = (unsigned short*)((char*)d_ws + 92165376);
    unsigned short* s1     = bws;                  // tgtb -> ctxb -> tb -> t2b
    unsigned short* tgtb   = s1;
    unsigned short* ctxb   = s1;
    unsigned short* tb     = s1;
    unsigned short* t2b    = s1;
    unsigned short* s2     = bws + 7372800;        // qkvb / valueb+msoutb
    unsigned short* qkvb   = s2;
    unsigned short* valueb = s2;
    unsigned short* msoutb = s2 + 9676800;
    unsigned short* srcb   = bws + 36864000;
    unsigned short* wtsb   = bws + 46540800;       // 991,232 shorts

    // 1. merged prep (conversions + weight cast + query_pos projections)
    prep_kernel<<<17623, 256, 0, stream>>>(tgt, tgtb, src, srcb,
                                           in_proj_w, out_proj_w, value_proj_w,
                                           cross_out_w, samp_off_w, attn_w_w,
                                           ffn_w1, ffn_w2, wtsb,
                                           qp, samp_off_b, attn_w_b, qpv);
    // 2. QKV projection (Q,K cols get query_pos bias via qpv, cols < 512)
    gemm_bf16<<<dim3(225, 6), 256, 0, stream>>>(tgtb, wtsb + 0, in_proj_b, qpv, 512,
                                                nullptr, qkvb, MROWS, 768, 256, 0);
    // 3. self-attention over batch axis
    self_attn_kernel<<<3600, 256, 0, stream>>>(qkvb, ctxb);
    // 4. t = LN2(tgt + out_proj(ctx))   [fused; in-place ctxb->tb safe]
    gemm_ln<<<450, 256, 0, stream>>>(ctxb, wtsb + 196608, out_proj_b, tgt,
                                     ln2_g, ln2_b, t, tb, 256);
    // 5. value projection (M = 37800)
    gemm_bf16<<<dim3(296, 2), 256, 0, stream>>>(srcb, wtsb + 262144, value_proj_b, nullptr, 0,
                                                nullptr, valueb, BATCH * LIN, 256, 256, 0);
    // 6. fused sampling-offset + attn-weight projection (N = 288)
    gemm_bf16<<<dim3(225, 3), 256, 0, stream>>>(tb, wtsb + 393216, cbias, nullptr, 0,
                                                comb, nullptr, MROWS, 288, 256, 0);
    // 7. packed sampling metadata (in place over comb)
    msprep_kernel<<<900, 256, 0, stream>>>(comb);
    // 8. deformable sampling (hot)
    msdeform_kernel<<<7200, 256, 0, stream>>>(valueb, (const unsigned int*)comb, msoutb);
    // 9. t2 = LN1(t + cross_out(msout))   [fused]
    gemm_ln<<<450, 256, 0, stream>>>(msoutb, wtsb + 327680, cross_out_b, t,
                                     ln1_g, ln1_b, t2, t2b, 256);
    // 10. out = LN3(t2 + FFN(t2))   [fully fused; hidden never hits HBM]
    ffn_fused_kernel<<<900, 256, 0, stream>>>(t2b, wtsb + 466944, ffn_b1,
                                              wtsb + 729088, ffn_b2, t2,
                                              ln3_g, ln3_b, out);
}

// Round 8
// 470.684 us; speedup vs baseline: 1.0905x; 1.0343x over previous
//
#include <hip/hip_runtime.h>
#include <hip/hip_bf16.h>
#include <cstddef>
#include <cstdint>

// Problem constants
#define D_MODEL 256
#define NHEAD   8
#define HDIM    32
#define NLEV    3
#define NPNT    4
#define DFF     1024
#define BATCH   8
#define LQ      3600
#define LIN     4725   // 60*60 + 30*30 + 15*15
#define MROWS   (BATCH*LQ)   // 28800; row order is (lq,b): m = lq*8 + b

typedef short bf16x8 __attribute__((ext_vector_type(8)));
typedef float f32x4  __attribute__((ext_vector_type(4)));

__device__ __forceinline__ unsigned short f2b(float x) {
    unsigned int u = __float_as_uint(x);
    unsigned int r = (u + 0x7fffu + ((u >> 16) & 1u)) >> 16;   // RNE
    return (unsigned short)r;
}
__device__ __forceinline__ float b2f(unsigned short s) {
    return __uint_as_float(((unsigned int)s) << 16);
}

#define GLDS16(g, l) __builtin_amdgcn_global_load_lds( \
    (const __attribute__((address_space(1))) void*)(g), \
    (__attribute__((address_space(3))) void*)(l), 16, 0, 0)

// ---------------------------------------------------------------------------
// Merged prep: [0,7200) conv tgt->bf16; [7200,16650) conv src->bf16;
// [16650,17618) weight convert; [17618,17623) query_pos projections.
#define WTOT 991232
__global__ __launch_bounds__(256) void prep_kernel(
    const float* __restrict__ tgt, unsigned short* __restrict__ tgtb,
    const float* __restrict__ srcf, unsigned short* __restrict__ srcb,
    const float* __restrict__ w_in, const float* __restrict__ w_out,
    const float* __restrict__ w_val, const float* __restrict__ w_cross,
    const float* __restrict__ w_so, const float* __restrict__ w_aw,
    const float* __restrict__ w_f1, const float* __restrict__ w_f2,
    unsigned short* __restrict__ wdst,
    const float* __restrict__ qp, const float* __restrict__ so_b,
    const float* __restrict__ aw_b, float* __restrict__ qpv)
{
    const int bid = blockIdx.x;
    const int tid = threadIdx.x;
    if (bid < 7200) {
        int i = bid * 256 + tid;
        float4 v = ((const float4*)tgt)[i];
        ushort4 o; o.x = f2b(v.x); o.y = f2b(v.y); o.z = f2b(v.z); o.w = f2b(v.w);
        ((ushort4*)tgtb)[i] = o;
    } else if (bid < 16650) {
        int i = (bid - 7200) * 256 + tid;
        float4 v = ((const float4*)srcf)[i];
        ushort4 o; o.x = f2b(v.x); o.y = f2b(v.y); o.z = f2b(v.z); o.w = f2b(v.w);
        ((ushort4*)srcb)[i] = o;
    } else if (bid < 17618) {
        int idx = ((bid - 16650) * 256 + tid) * 4;
        if (idx >= WTOT) return;
        const float* src; int off;
        if      (idx < 196608) { src = w_in;    off = idx; }
        else if (idx < 262144) { src = w_out;   off = idx - 196608; }
        else if (idx < 327680) { src = w_val;   off = idx - 262144; }
        else if (idx < 393216) { src = w_cross; off = idx - 327680; }
        else if (idx < 442368) { src = w_so;    off = idx - 393216; }
        else if (idx < 466944) { src = w_aw;    off = idx - 442368; }
        else if (idx < 729088) { src = w_f1;    off = idx - 466944; }
        else                   { src = w_f2;    off = idx - 729088; }
        float4 v = *(const float4*)(src + off);
        ushort4 o; o.x = f2b(v.x); o.y = f2b(v.y); o.z = f2b(v.z); o.w = f2b(v.w);
        *(ushort4*)(wdst + idx) = o;
    } else {
        int o = (bid - 17618) * 256 + tid;
        if (o >= 768 + 192 + 96) return;
        const float* wrow;
        if (o < 768)       wrow = w_in + (size_t)o * D_MODEL;
        else if (o < 960)  wrow = w_so + (size_t)(o - 768) * D_MODEL;
        else               wrow = w_aw + (size_t)(o - 960) * D_MODEL;
        float acc = 0.f;
        for (int d = 0; d < D_MODEL; ++d) acc += qp[d] * wrow[d];
        qpv[o] = acc;
        if (o >= 768) {
            float bias = (o < 960) ? so_b[o - 768] : aw_b[o - 960];
            qpv[1056 + (o - 768)] = acc + bias;
        }
    }
}

// ---------------------------------------------------------------------------
// bf16 MFMA GEMM (R4 proven version): 128x128 tile, BK=64 (2x32 panels),
// global_load_lds width=16 staging.
__global__ __launch_bounds__(256) void gemm_bf16(
    const unsigned short* __restrict__ A,
    const unsigned short* __restrict__ W,
    const float* __restrict__ bias,
    const float* __restrict__ bias2, int b2lim,
    float* __restrict__ Cf, unsigned short* __restrict__ Cb,
    int M, int N, int K, int relu)
{
    __shared__ __align__(16) unsigned short As[2 * 128 * 32];   // 16 KB
    __shared__ __align__(16) unsigned short Bs[2 * 128 * 32];   // 16 KB
    const int tid  = threadIdx.x;
    const int wave = tid >> 6;
    const int lane = tid & 63;
    const int m0 = blockIdx.x * 128;
    const int n0 = blockIdx.y * 128;

    const int lr  = lane >> 2;
    const int lc8 = (lane & 3) * 8;
    int ar0 = m0 + wave * 32 + lr;      if (ar0 > M - 1) ar0 = M - 1;
    int ar1 = m0 + wave * 32 + 16 + lr; if (ar1 > M - 1) ar1 = M - 1;
    int br0 = n0 + wave * 32 + lr;      if (br0 > N - 1) br0 = N - 1;
    int br1 = n0 + wave * 32 + 16 + lr; if (br1 > N - 1) br1 = N - 1;
    const unsigned short* pa0 = A + (size_t)ar0 * K + lc8;
    const unsigned short* pa1 = A + (size_t)ar1 * K + lc8;
    const unsigned short* pb0 = W + (size_t)br0 * K + lc8;
    const unsigned short* pb1 = W + (size_t)br1 * K + lc8;
    unsigned short* la0 = As + wave * 1024;
    unsigned short* la1 = As + wave * 1024 + 512;
    unsigned short* lb0 = Bs + wave * 1024;
    unsigned short* lb1 = Bs + wave * 1024 + 512;

    const int wm = (wave >> 1) * 64;
    const int wn = (wave & 1) * 64;
    const int fr = lane & 15;
    const int fk = (lane >> 4) * 8;

    f32x4 acc[4][4] = {};

    for (int k0 = 0; k0 < K; k0 += 64) {
        GLDS16(pa0, la0); GLDS16(pa0 + 32, la0 + 4096);
        GLDS16(pa1, la1); GLDS16(pa1 + 32, la1 + 4096);
        GLDS16(pb0, lb0); GLDS16(pb0 + 32, lb0 + 4096);
        GLDS16(pb1, lb1); GLDS16(pb1 + 32, lb1 + 4096);
        pa0 += 64; pa1 += 64; pb0 += 64; pb1 += 64;
        __syncthreads();
#pragma unroll
        for (int p = 0; p < 2; ++p) {
            bf16x8 af[4], bfv[4];
#pragma unroll
            for (int i = 0; i < 4; ++i)
                af[i] = *(const bf16x8*)&As[p * 4096 + (wm + i * 16 + fr) * 32 + fk];
#pragma unroll
            for (int j = 0; j < 4; ++j)
                bfv[j] = *(const bf16x8*)&Bs[p * 4096 + (wn + j * 16 + fr) * 32 + fk];
#pragma unroll
            for (int i = 0; i < 4; ++i)
#pragma unroll
                for (int j = 0; j < 4; ++j)
                    acc[i][j] = __builtin_amdgcn_mfma_f32_16x16x32_bf16(
                        af[i], bfv[j], acc[i][j], 0, 0, 0);
        }
        __syncthreads();
    }

    const int quad = lane >> 4;
#pragma unroll
    for (int j = 0; j < 4; ++j) {
        const int col = n0 + wn + j * 16 + fr;
        if (col >= N) continue;
        float bv = 0.f;
        if (bias) bv += bias[col];
        if (bias2 && col < b2lim) bv += bias2[col];
#pragma unroll
        for (int i = 0; i < 4; ++i) {
#pragma unroll
            for (int r = 0; r < 4; ++r) {
                const int row = m0 + wm + i * 16 + quad * 4 + r;
                if (row >= M) continue;
                float v = acc[i][j][r] + bv;
                if (relu) v = fmaxf(v, 0.f);
                if (Cf) Cf[(size_t)row * N + col] = v;
                if (Cb) Cb[(size_t)row * N + col] = f2b(v);
            }
        }
    }
}

// ---------------------------------------------------------------------------
// GEMM (N=256, full row per block) + residual + LayerNorm fused (R4 proven).
__global__ __launch_bounds__(256) void gemm_ln(
    const unsigned short* __restrict__ A,    // M x K bf16
    const unsigned short* __restrict__ W,    // 256 x K bf16
    const float* __restrict__ bias,          // 256
    const float* __restrict__ resid,         // M x 256 fp32
    const float* __restrict__ g, const float* __restrict__ bb,
    float* __restrict__ outf, unsigned short* __restrict__ outb, int K)
{
    __shared__ __align__(16) unsigned short As[2 * 64 * 32];    // 8 KB
    __shared__ __align__(16) unsigned short Bs[2 * 256 * 32];   // 32 KB
    const int tid  = threadIdx.x;
    const int wave = tid >> 6;
    const int lane = tid & 63;
    const int m0 = blockIdx.x * 64;

    const int arow = tid >> 2;
    const int akc  = (tid & 3) * 8;
    const unsigned short* pa = A + (size_t)(m0 + arow) * K + akc;
    unsigned short* la = As + tid * 8;
    const unsigned short* pb0 = W + (size_t)(arow)       * K + akc;
    const unsigned short* pb1 = W + (size_t)(64  + arow) * K + akc;
    const unsigned short* pb2 = W + (size_t)(128 + arow) * K + akc;
    const unsigned short* pb3 = W + (size_t)(192 + arow) * K + akc;
    unsigned short* lb0 = Bs + tid * 8;
    unsigned short* lb1 = Bs + 2048 + tid * 8;
    unsigned short* lb2 = Bs + 4096 + tid * 8;
    unsigned short* lb3 = Bs + 6144 + tid * 8;

    const int fr = lane & 15;
    const int fk = (lane >> 4) * 8;
    const int quad = lane >> 4;
    const int colbase = wave * 64;

    f32x4 acc[4][4] = {};

    for (int k0 = 0; k0 < K; k0 += 64) {
        GLDS16(pa, la);        GLDS16(pa + 32, la + 2048);
        GLDS16(pb0, lb0);      GLDS16(pb0 + 32, lb0 + 8192);
        GLDS16(pb1, lb1);      GLDS16(pb1 + 32, lb1 + 8192);
        GLDS16(pb2, lb2);      GLDS16(pb2 + 32, lb2 + 8192);
        GLDS16(pb3, lb3);      GLDS16(pb3 + 32, lb3 + 8192);
        pa += 64; pb0 += 64; pb1 += 64; pb2 += 64; pb3 += 64;
        __syncthreads();
#pragma unroll
        for (int p = 0; p < 2; ++p) {
            bf16x8 af[4], bfv[4];
#pragma unroll
            for (int i = 0; i < 4; ++i)
                af[i] = *(const bf16x8*)&As[p * 2048 + (i * 16 + fr) * 32 + fk];
#pragma unroll
            for (int j = 0; j < 4; ++j)
                bfv[j] = *(const bf16x8*)&Bs[p * 8192 + (colbase + j * 16 + fr) * 32 + fk];
#pragma unroll
            for (int i = 0; i < 4; ++i)
#pragma unroll
                for (int j = 0; j < 4; ++j)
                    acc[i][j] = __builtin_amdgcn_mfma_f32_16x16x32_bf16(
                        af[i], bfv[j], acc[i][j], 0, 0, 0);
        }
        __syncthreads();
    }

    // ---- fused epilogue: v = acc + bias + resid; LN over 256 cols ----
    float2* red = (float2*)As;   // 256 entries, aliases As (post-barrier safe)
    float rs[4][4], rq[4][4];
#pragma unroll
    for (int i = 0; i < 4; ++i) {
#pragma unroll
        for (int r = 0; r < 4; ++r) {
            const int row = m0 + i * 16 + quad * 4 + r;
            float s = 0.f, q = 0.f;
#pragma unroll
            for (int j = 0; j < 4; ++j) {
                const int col = colbase + j * 16 + fr;
                float v = acc[i][j][r] + bias[col] + resid[(size_t)row * 256 + col];
                acc[i][j][r] = v;
                s += v; q += v * v;
            }
            rs[i][r] = s; rq[i][r] = q;
        }
    }
#pragma unroll
    for (int off = 1; off < 16; off <<= 1) {
#pragma unroll
        for (int i = 0; i < 4; ++i)
#pragma unroll
            for (int r = 0; r < 4; ++r) {
                rs[i][r] += __shfl_xor(rs[i][r], off);
                rq[i][r] += __shfl_xor(rq[i][r], off);
            }
    }
    if ((lane & 15) == 0) {
#pragma unroll
        for (int i = 0; i < 4; ++i)
#pragma unroll
            for (int r = 0; r < 4; ++r)
                red[wave * 64 + i * 16 + quad * 4 + r] = make_float2(rs[i][r], rq[i][r]);
    }
    __syncthreads();
#pragma unroll
    for (int i = 0; i < 4; ++i) {
#pragma unroll
        for (int r = 0; r < 4; ++r) {
            const int rl = i * 16 + quad * 4 + r;
            const float2 t0 = red[rl], t1 = red[64 + rl], t2 = red[128 + rl], t3 = red[192 + rl];
            const float sum = t0.x + t1.x + t2.x + t3.x;
            const float sq  = t0.y + t1.y + t2.y + t3.y;
            const float mean = sum * (1.f / 256.f);
            const float var  = sq * (1.f / 256.f) - mean * mean;
            const float inv  = rsqrtf(var + 1e-5f);
            const int row = m0 + rl;
#pragma unroll
            for (int j = 0; j < 4; ++j) {
                const int col = colbase + j * 16 + fr;
                const float val = (acc[i][j][r] - mean) * inv * g[col] + bb[col];
                outf[(size_t)row * 256 + col] = val;
                if (outb) outb[(size_t)row * 256 + col] = f2b(val);
            }
        }
    }
}

// ---------------------------------------------------------------------------
// Fully fused FFN with XOR-swizzled LDS layouts (bank-conflict fix).
// 16-B chunk (row, k8) of a tile is stored at LDS slot row*NK + (k8 ^ (row&7));
// GLDS16 staging lanes fetch the correspondingly permuted global chunk (XOR
// permutes within a row -> global coalescing unchanged). Fragment reads then
// hit banks 4*((k8^fr)&7): same 8-lanes/bank distribution as gemm_bf16
// (measured 0 conflicts). hid uses padded stride 72 shorts (144 B).
// LDS: Ab 16K + Wc 32K + hid 4.5K = 52.5 KB -> 3 blocks/CU.
__global__ __launch_bounds__(256) void ffn_fused_kernel(
    const unsigned short* __restrict__ A,     // M x 256 bf16 (t2b)
    const unsigned short* __restrict__ W1,    // 1024 x 256 bf16
    const float* __restrict__ b1,             // 1024
    const unsigned short* __restrict__ W2,    // 256 x 1024 bf16
    const float* __restrict__ b2,             // 256
    const float* __restrict__ resid,          // M x 256 fp32 (t2)
    const float* __restrict__ g, const float* __restrict__ bb,
    float* __restrict__ outf)
{
    __shared__ __align__(16) unsigned short Ab[8192];    // 32 rows x 32 k8-slots
    __shared__ __align__(16) unsigned short Wc[16384];   // W1: 64x32 / W2: 256x8 slots
    __shared__ __align__(16) unsigned short hid[2304];   // 32 x 72 (padded)
    const int tid  = threadIdx.x;
    const int wave = tid >> 6;
    const int lane = tid & 63;
    const int m0 = blockIdx.x * 32;
    const int fr   = lane & 15;
    const int quad = lane >> 4;
    const int xm   = fr & 7;           // XOR mask for fragment reads

    // ---- stage A (32 rows): swizzled. Wave-load c covers rows {2c,2c+1}. ----
#pragma unroll
    for (int j = 0; j < 4; ++j) {
        const int c  = wave * 4 + j;               // 0..15
        const int rA = c * 2 + (lane >> 5);        // row 0..31
        const int k8 = (lane & 31) ^ (rA & 7);
        GLDS16(A + (size_t)(m0 + rA) * 256 + k8 * 8, Ab + c * 512);
    }
    // ---- precompute per-lane swizzled staging offsets for W1 / W2 ----
    int w1off[8], w2off[8];
#pragma unroll
    for (int j = 0; j < 8; ++j) {
        const int c  = wave * 8 + j;               // 0..31
        const int n1 = c * 2 + (lane >> 5);        // W1 row in chunk 0..63
        const int k1 = (lane & 31) ^ (n1 & 7);
        w1off[j] = n1 * 256 + k1 * 8;              // + h*16384
        const int n2 = c * 8 + (lane >> 3);        // W2 row 0..255
        const int k2 = (lane & 7) ^ (n2 & 7);
        w2off[j] = n2 * 1024 + k2 * 8;             // + h*64
    }
    __syncthreads();
    bf16x8 af[2][8];
#pragma unroll
    for (int i = 0; i < 2; ++i)
#pragma unroll
        for (int s = 0; s < 8; ++s)
            af[i][s] = *(const bf16x8*)&Ab[((i * 16 + fr) * 32 + ((s * 4 + quad) ^ xm)) * 8];

    f32x4 acc2[2][4] = {};

    for (int h = 0; h < 16; ++h) {
        __syncthreads();   // prior gemm2's Wc reads done
        // stage W1 chunk (rows 64h..64h+63), swizzled
#pragma unroll
        for (int j = 0; j < 8; ++j)
            GLDS16(W1 + (size_t)h * 16384 + w1off[j], Wc + (wave * 8 + j) * 512);
        __syncthreads();
        // gemm1: wave w -> hidden cols [16w, 16w+16)
        f32x4 acc1[2] = {};
#pragma unroll
        for (int s = 0; s < 8; ++s) {
            bf16x8 bv = *(const bf16x8*)&Wc[((wave * 16 + fr) * 32 + ((s * 4 + quad) ^ xm)) * 8];
            acc1[0] = __builtin_amdgcn_mfma_f32_16x16x32_bf16(af[0][s], bv, acc1[0], 0, 0, 0);
            acc1[1] = __builtin_amdgcn_mfma_f32_16x16x32_bf16(af[1][s], bv, acc1[1], 0, 0, 0);
        }
        const float bias1 = b1[h * 64 + wave * 16 + fr];
#pragma unroll
        for (int i = 0; i < 2; ++i)
#pragma unroll
            for (int r = 0; r < 4; ++r) {
                float v = fmaxf(acc1[i][r] + bias1, 0.f);
                hid[(i * 16 + quad * 4 + r) * 72 + wave * 16 + fr] = f2b(v);
            }
        __syncthreads();   // hid ready; Wc reads done
        // stage W2 chunk (k-slice [64h,64h+64)), swizzled
#pragma unroll
        for (int j = 0; j < 8; ++j)
            GLDS16(W2 + (size_t)h * 64 + w2off[j], Wc + (wave * 8 + j) * 512);
        __syncthreads();
        // gemm2: wave w -> out cols [64w, 64w+64); k = 64 (2 steps)
#pragma unroll
        for (int s = 0; s < 2; ++s) {
            bf16x8 a2[2], b2v[4];
#pragma unroll
            for (int i = 0; i < 2; ++i)
                a2[i] = *(const bf16x8*)&hid[(i * 16 + fr) * 72 + s * 32 + quad * 8];
#pragma unroll
            for (int j2 = 0; j2 < 4; ++j2) {
                const int nb = wave * 64 + j2 * 16 + fr;
                b2v[j2] = *(const bf16x8*)&Wc[(nb * 8 + ((s * 4 + quad) ^ xm)) * 8];
            }
#pragma unroll
            for (int i = 0; i < 2; ++i)
#pragma unroll
                for (int j2 = 0; j2 < 4; ++j2)
                    acc2[i][j2] = __builtin_amdgcn_mfma_f32_16x16x32_bf16(
                        a2[i], b2v[j2], acc2[i][j2], 0, 0, 0);
        }
    }

    // ---- epilogue: v = acc2 + b2 + resid; LN over 256 cols ----
    __syncthreads();                    // all hid reads done; reuse hid as red
    float2* red = (float2*)hid;         // 128 float2 = 1 KB
    const int colbase = wave * 64;
    float rs[2][4], rq[2][4];
#pragma unroll
    for (int x = 0; x < 2; ++x) {
#pragma unroll
        for (int r = 0; r < 4; ++r) {
            const int row = m0 + x * 16 + quad * 4 + r;
            float s = 0.f, q = 0.f;
#pragma unroll
            for (int y = 0; y < 4; ++y) {
                const int col = colbase + y * 16 + fr;
                float v = acc2[x][y][r] + b2[col] + resid[(size_t)row * 256 + col];
                acc2[x][y][r] = v;
                s += v; q += v * v;
            }
            rs[x][r] = s; rq[x][r] = q;
        }
    }
#pragma unroll
    for (int off = 1; off < 16; off <<= 1) {
#pragma unroll
        for (int x = 0; x < 2; ++x)
#pragma unroll
            for (int r = 0; r < 4; ++r) {
                rs[x][r] += __shfl_xor(rs[x][r], off);
                rq[x][r] += __shfl_xor(rq[x][r], off);
            }
    }
    if ((lane & 15) == 0) {
#pragma unroll
        for (int x = 0; x < 2; ++x)
#pragma unroll
            for (int r = 0; r < 4; ++r)
                red[wave * 32 + x * 16 + quad * 4 + r] = make_float2(rs[x][r], rq[x][r]);
    }
    __syncthreads();
#pragma unroll
    for (int x = 0; x < 2; ++x) {
#pragma unroll
        for (int r = 0; r < 4; ++r) {
            const int rl = x * 16 + quad * 4 + r;
            const float2 t0 = red[rl], t1 = red[32 + rl], t2 = red[64 + rl], t3 = red[96 + rl];
            const float sum = t0.x + t1.x + t2.x + t3.x;
            const float sq  = t0.y + t1.y + t2.y + t3.y;
            const float mean = sum * (1.f / 256.f);
            const float var  = sq * (1.f / 256.f) - mean * mean;
            const float inv  = rsqrtf(var + 1e-5f);
            const int row = m0 + rl;
#pragma unroll
            for (int y = 0; y < 4; ++y) {
                const int col = colbase + y * 16 + fr;
                outf[(size_t)row * 256 + col] = (acc2[x][y][r] - mean) * inv * g[col] + bb[col];
            }
        }
    }
}

// ---------------------------------------------------------------------------
// Self-attention over S=8 (batch axis). Row order (lq,b): row = n*8 + s.
__global__ __launch_bounds__(256) void self_attn_kernel(
    const unsigned short* __restrict__ qkv, unsigned short* __restrict__ ctx)
{
    __shared__ float sh[8][768];
    __shared__ float ls[8][8][8];   // [h][s][t]
    const int n = blockIdx.x;
    const int t = threadIdx.x;
#pragma unroll
    for (int s = 0; s < 8; ++s) {
        const unsigned short* row = qkv + (size_t)(n * 8 + s) * 768;
        sh[s][t]       = b2f(row[t]);
        sh[s][t + 256] = b2f(row[t + 256]);
        sh[s][t + 512] = b2f(row[t + 512]);
    }
    __syncthreads();
    const int h = t >> 5, j = t & 31;
#pragma unroll
    for (int pair = j; pair < 64; pair += 32) {
        const int s = pair >> 3, tt = pair & 7;
        float acc = 0.f;
#pragma unroll
        for (int d = 0; d < 32; ++d)
            acc += sh[s][h * 32 + d] * sh[tt][256 + h * 32 + d];
        ls[h][s][tt] = acc * 0.17677669529663687f;
    }
    __syncthreads();
    if (t < 64) {
        const int hh = t >> 3, s = t & 7;
        float mx = -1e30f;
        for (int tt = 0; tt < 8; ++tt) mx = fmaxf(mx, ls[hh][s][tt]);
        float sum = 0.f;
        for (int tt = 0; tt < 8; ++tt) { float e = expf(ls[hh][s][tt] - mx); ls[hh][s][tt] = e; sum += e; }
        const float inv = 1.f / sum;
        for (int tt = 0; tt < 8; ++tt) ls[hh][s][tt] *= inv;
    }
    __syncthreads();
#pragma unroll
    for (int s = 0; s < 8; ++s) {
        float acc = 0.f;
#pragma unroll
        for (int tt = 0; tt < 8; ++tt)
            acc += ls[h][s][tt] * sh[tt][512 + h * 32 + j];
        ctx[(size_t)(n * 8 + s) * D_MODEL + h * 32 + j] = f2b(acc);
    }
}

// ---------------------------------------------------------------------------
// msprep: one thread per (m,h); softmax + bilinear setup once, packed 12 B/pt,
// written in place over comb rows (whole rows per block; barrier between).
__global__ __launch_bounds__(256) void msprep_kernel(float* __restrict__ comb)
{
    const int tid = threadIdx.x;
    const int m = blockIdx.x * 32 + (tid >> 3);
    const int h = tid & 7;
    const int lq = m >> 3;
    const float* offp = comb + (size_t)m * 288 + h * 24;
    const float* awp  = comb + (size_t)m * 288 + 192 + h * 12;
    float off[24], aw[12];
#pragma unroll
    for (int i = 0; i < 6; ++i) *(float4*)&off[i * 4] = ((const float4*)offp)[i];
#pragma unroll
    for (int i = 0; i < 3; ++i) *(float4*)&aw[i * 4] = ((const float4*)awp)[i];

    float mx = aw[0];
#pragma unroll
    for (int i = 1; i < 12; ++i) mx = fmaxf(mx, aw[i]);
    float se = 0.f;
#pragma unroll
    for (int i = 0; i < 12; ++i) { aw[i] = __expf(aw[i] - mx); se += aw[i]; }
    const float inv = 1.f / se;

    const float refx = ((lq % 60) + 0.5f) * (1.f / 60.f);
    const float refy = ((lq / 60) + 0.5f) * (1.f / 60.f);
    const int HW[3] = {60, 30, 15};
    const int ST[3] = {0, 3600, 4500};

    unsigned int outv[36];
#pragma unroll
    for (int lev = 0; lev < NLEV; ++lev) {
        const int Wl = HW[lev], Hl = HW[lev], s0 = ST[lev];
        const float fWl = (float)Wl, fHl = (float)Hl;
#pragma unroll
        for (int p = 0; p < NPNT; ++p) {
            const int pt = lev * 4 + p;
            const float ox = off[lev * 8 + p * 2];
            const float oy = off[lev * 8 + p * 2 + 1];
            const float px = refx * fWl + ox - 0.5f;
            const float py = refy * fHl + oy - 0.5f;
            const float x0f = floorf(px), y0f = floorf(py);
            const float fx = px - x0f, fy = py - y0f;
            const int x0 = (int)x0f, y0 = (int)y0f;
            const float aww = aw[pt] * inv;
            const float vx0 = (x0 >= 0 && x0 < Wl) ? 1.f : 0.f;
            const float vx1 = (x0 >= -1 && x0 < Wl - 1) ? 1.f : 0.f;
            const float vy0 = (y0 >= 0 && y0 < Hl) ? 1.f : 0.f;
            const float vy1 = (y0 >= -1 && y0 < Hl - 1) ? 1.f : 0.f;
            const int xc0 = min(max(x0, 0), Wl - 1);
            const int xc1 = min(max(x0 + 1, 0), Wl - 1);
            const int yc0 = min(max(y0, 0), Hl - 1);
            const int yc1 = min(max(y0 + 1, 0), Hl - 1);
            const unsigned int sx  = (unsigned int)(xc1 - xc0);
            const unsigned int syW = (unsigned int)((yc1 - yc0) * Wl);
            const unsigned int idx = (unsigned int)(s0 + yc0 * Wl + xc0);
            const float w00 = (1.f - fx) * (1.f - fy) * aww * vx0 * vy0;
            const float w01 = fx * (1.f - fy) * aww * vx1 * vy0;
            const float w10 = (1.f - fx) * fy * aww * vx0 * vy1;
            const float w11 = fx * fy * aww * vx1 * vy1;
            outv[pt * 3]     = idx | (sx << 16) | (syW << 17);
            outv[pt * 3 + 1] = (unsigned int)f2b(w00) | ((unsigned int)f2b(w01) << 16);
            outv[pt * 3 + 2] = (unsigned int)f2b(w10) | ((unsigned int)f2b(w11) << 16);
        }
    }
    __syncthreads();
    uint4* dst = (uint4*)((char*)comb + (size_t)m * 1152 + h * 144);
#pragma unroll
    for (int i = 0; i < 9; ++i) dst[i] = *(uint4*)&outv[i * 4];
}

// ---------------------------------------------------------------------------
// Hot deformable sampling (unchanged).
__global__ __launch_bounds__(256) void msdeform_kernel(
    const unsigned short* __restrict__ value,
    const unsigned int* __restrict__ meta,
    unsigned short* __restrict__ out)
{
    const int bid = blockIdx.x;
    const int b   = bid & 7;
    const int lq0 = (bid >> 3) * 4;
    const int r    = threadIdx.x >> 6;
    const int lane = threadIdx.x & 63;
    const int h = lane >> 3;
    const int l = lane & 7;
    const int m = (lq0 + r) * 8 + b;

    const unsigned int* mp = meta + (size_t)m * 288 + h * 36;
    uint4 md[9];
#pragma unroll
    for (int i = 0; i < 9; ++i) md[i] = ((const uint4*)mp)[i];
    const unsigned int* mw = (const unsigned int*)md;

    const unsigned short* vbase = value + (size_t)b * LIN * 256 + h * 32 + l * 4;

    float a0 = 0.f, a1 = 0.f, a2 = 0.f, a3 = 0.f;
#pragma unroll
    for (int p = 0; p < 12; ++p) {
        const unsigned int pack = mw[p * 3];
        const unsigned int wlo  = mw[p * 3 + 1];
        const unsigned int whi  = mw[p * 3 + 2];
        const unsigned int i00 = pack & 0xFFFFu;
        const unsigned int sx  = (pack >> 16) & 1u;
        const unsigned int syW = pack >> 17;
        const unsigned int i01 = i00 + sx;
        const unsigned int i10 = i00 + syW;
        const unsigned int i11 = i10 + sx;
        const float w00 = __uint_as_float(wlo << 16);
        const float w01 = __uint_as_float(wlo & 0xFFFF0000u);
        const float w10 = __uint_as_float(whi << 16);
        const float w11 = __uint_as_float(whi & 0xFFFF0000u);
        const ushort4 g00 = *(const ushort4*)(vbase + (size_t)i00 * 256);
        const ushort4 g01 = *(const ushort4*)(vbase + (size_t)i01 * 256);
        const ushort4 g10 = *(const ushort4*)(vbase + (size_t)i10 * 256);
        const ushort4 g11 = *(const ushort4*)(vbase + (size_t)i11 * 256);
        a0 += b2f(g00.x) * w00 + b2f(g01.x) * w01 + b2f(g10.x) * w10 + b2f(g11.x) * w11;
        a1 += b2f(g00.y) * w00 + b2f(g01.y) * w01 + b2f(g10.y) * w10 + b2f(g11.y) * w11;
        a2 += b2f(g00.z) * w00 + b2f(g01.z) * w01 + b2f(g10.z) * w10 + b2f(g11.z) * w11;
        a3 += b2f(g00.w) * w00 + b2f(g01.w) * w01 + b2f(g10.w) * w10 + b2f(g11.w) * w11;
    }
    ushort4 o;
    o.x = f2b(a0); o.y = f2b(a1); o.z = f2b(a2); o.w = f2b(a3);
    *(ushort4*)(out + (size_t)m * 256 + h * 32 + l * 4) = o;
}

// ---------------------------------------------------------------------------
extern "C" void kernel_launch(void* const* d_in, const int* in_sizes, int n_in,
                              void* d_out, int out_size, void* d_ws, size_t ws_size,
                              hipStream_t stream)
{
    (void)in_sizes; (void)n_in; (void)out_size; (void)ws_size;
    const float* tgt          = (const float*)d_in[0];   // (LQ,B,D): (lq,b)-major rows
    const float* qp           = (const float*)d_in[1];
    const float* src          = (const float*)d_in[2];
    const float* in_proj_w    = (const float*)d_in[5];
    const float* in_proj_b    = (const float*)d_in[6];
    const float* out_proj_w   = (const float*)d_in[7];
    const float* out_proj_b   = (const float*)d_in[8];
    const float* samp_off_w   = (const float*)d_in[9];
    const float* samp_off_b   = (const float*)d_in[10];
    const float* attn_w_w     = (const float*)d_in[11];
    const float* attn_w_b     = (const float*)d_in[12];
    const float* value_proj_w = (const float*)d_in[13];
    const float* value_proj_b = (const float*)d_in[14];
    const float* cross_out_w  = (const float*)d_in[15];
    const float* cross_out_b  = (const float*)d_in[16];
    const float* ln1_g = (const float*)d_in[17];
    const float* ln1_b = (const float*)d_in[18];
    const float* ln2_g = (const float*)d_in[19];
    const float* ln2_b = (const float*)d_in[20];
    const float* ln3_g = (const float*)d_in[21];
    const float* ln3_b = (const float*)d_in[22];
    const float* ffn_w1 = (const float*)d_in[23];
    const float* ffn_b1 = (const float*)d_in[24];
    const float* ffn_w2 = (const float*)d_in[25];
    const float* ffn_b2 = (const float*)d_in[26];
    float* out = (float*)d_out;

    // ---- fp32 arena (floats) ----
    float* ws    = (float*)d_ws;
    float* t     = ws;                    // LN2 out (residual for LN1)
    float* t2    = ws + 7372800;          // LN1 out (residual for LN3)
    float* comb  = ws + 14745600;         // 28800x288 off+aw -> msprep packed
    float* qpv   = ws + 23040000;         // 1056 qp-proj + 288 cbias
    float* cbias = qpv + 1056;

    // ---- bf16 arena (ushort), after fp32 arena (byte 92,165,376) ----
    unsigned short* bws    = (unsigned short*)((char*)d_ws + 92165376);
    unsigned short* s1     = bws;                  // tgtb -> ctxb -> tb -> t2b
    unsigned short* tgtb   = s1;
    unsigned short* ctxb   = s1;
    unsigned short* tb     = s1;
    unsigned short* t2b    = s1;
    unsigned short* s2     = bws + 7372800;        // qkvb / valueb+msoutb
    unsigned short* qkvb   = s2;
    unsigned short* valueb = s2;
    unsigned short* msoutb = s2 + 9676800;
    unsigned short* srcb   = bws + 36864000;
    unsigned short* wtsb   = bws + 46540800;       // 991,232 shorts

    // 1. merged prep (conversions + weight cast + query_pos projections)
    prep_kernel<<<17623, 256, 0, stream>>>(tgt, tgtb, src, srcb,
                                           in_proj_w, out_proj_w, value_proj_w,
                                           cross_out_w, samp_off_w, attn_w_w,
                                           ffn_w1, ffn_w2, wtsb,
                                           qp, samp_off_b, attn_w_b, qpv);
    // 2. QKV projection (Q,K cols get query_pos bias via qpv, cols < 512)
    gemm_bf16<<<dim3(225, 6), 256, 0, stream>>>(tgtb, wtsb + 0, in_proj_b, qpv, 512,
                                                nullptr, qkvb, MROWS, 768, 256, 0);
    // 3. self-attention over batch axis
    self_attn_kernel<<<3600, 256, 0, stream>>>(qkvb, ctxb);
    // 4. t = LN2(tgt + out_proj(ctx))   [fused; in-place ctxb->tb safe]
    gemm_ln<<<450, 256, 0, stream>>>(ctxb, wtsb + 196608, out_proj_b, tgt,
                                     ln2_g, ln2_b, t, tb, 256);
    // 5. value projection (M = 37800)
    gemm_bf16<<<dim3(296, 2), 256, 0, stream>>>(srcb, wtsb + 262144, value_proj_b, nullptr, 0,
                                                nullptr, valueb, BATCH * LIN, 256, 256, 0);
    // 6. fused sampling-offset + attn-weight projection (N = 288)
    gemm_bf16<<<dim3(225, 3), 256, 0, stream>>>(tb, wtsb + 393216, cbias, nullptr, 0,
                                                comb, nullptr, MROWS, 288, 256, 0);
    // 7. packed sampling metadata (in place over comb)
    msprep_kernel<<<900, 256, 0, stream>>>(comb);
    // 8. deformable sampling (hot)
    msdeform_kernel<<<7200, 256, 0, stream>>>(valueb, (const unsigned int*)comb, msoutb);
    // 9. t2 = LN1(t + cross_out(msout))   [fused]
    gemm_ln<<<450, 256, 0, stream>>>(msoutb, wtsb + 327680, cross_out_b, t,
                                     ln1_g, ln1_b, t2, t2b, 256);
    // 10. out = LN3(t2 + FFN(t2))   [fully fused; hidden never hits HBM]
    ffn_fused_kernel<<<900, 256, 0, stream>>>(t2b, wtsb + 466944, ffn_b1,
                                              wtsb + 729088, ffn_b2, t2,
                                              ln3_g, ln3_b, out);
}